// Round 8
// baseline (578.270 us; speedup 1.0000x reference)
//
#include <hip/hip_runtime.h>

#define F_ATOM 70

#define FLAG_RELU 1
#define FLAG_BN   2
#define FLAG_RES  4

typedef __attribute__((ext_vector_type(8))) short short8;
typedef __attribute__((ext_vector_type(4))) float floatx4;

__device__ __forceinline__ float bf2f(unsigned short u) {
    union { unsigned int i; float f; } x; x.i = (unsigned int)u << 16; return x.f;
}
__device__ __forceinline__ unsigned short f2bf(float f) {
    union { float f; unsigned int i; } x; x.f = f;
    unsigned int r = x.i + 0x7fffu + ((x.i >> 16) & 1u);
    return (unsigned short)(r >> 16);
}
__device__ __forceinline__ float blo(unsigned int u){ union{unsigned int a; float f;}x; x.a=u<<16; return x.f; }
__device__ __forceinline__ float bhi(unsigned int u){ union{unsigned int a; float f;}x; x.a=u&0xffff0000u; return x.f; }

// ---------------- CSR build ----------------

__global__ void count_kernel(const int* __restrict__ dst, int* __restrict__ cnt, int E) {
    int i = blockIdx.x * blockDim.x + threadIdx.x;
    if (i < E) atomicAdd(&cnt[dst[i]], 1);
}

__global__ void scan_kernel(const int* __restrict__ cnt, int* __restrict__ offs, int n) {
    __shared__ int wsum[16];
    __shared__ int carry_s;
    int t = threadIdx.x, lane = t & 63, wid = t >> 6;
    if (t == 0) carry_s = 0;
    __syncthreads();
    for (int base = 0; base < n; base += 1024) {
        int idx = base + t;
        int v = (idx < n) ? cnt[idx] : 0;
        int s = v;
        #pragma unroll
        for (int o = 1; o < 64; o <<= 1) {
            int x = __shfl_up(s, o);
            if (lane >= o) s += x;
        }
        if (lane == 63) wsum[wid] = s;
        __syncthreads();
        int woff = 0;
        #pragma unroll
        for (int wI = 0; wI < 16; ++wI) woff += (wI < wid) ? wsum[wI] : 0;
        int carry = carry_s;
        if (idx < n) offs[idx] = carry + woff + s - v;
        __syncthreads();
        if (t == 1023) carry_s = carry + woff + s;
        __syncthreads();
    }
    if (threadIdx.x == 0) offs[n] = carry_s;
}

__global__ void fill_kernel(const int* __restrict__ src, const int* __restrict__ dst,
                            const int* __restrict__ offs, int* __restrict__ cursor,
                            int* __restrict__ ssrc, int E) {
    int i = blockIdx.x * blockDim.x + threadIdx.x;
    if (i < E) {
        int d = dst[i];
        int pos = atomicAdd(&cursor[d], 1);
        ssrc[offs[d] + pos] = src[i];
    }
}

__global__ void graph_bounds_kernel(const int* __restrict__ batch, int* __restrict__ goffs,
                                    int N, int B) {
    int g = blockIdx.x * blockDim.x + threadIdx.x;
    if (g > B) return;
    int lo = 0, hi = N;
    while (lo < hi) {
        int mid = (lo + hi) >> 1;
        if (batch[mid] < g) lo = mid + 1; else hi = mid;
    }
    goffs[g] = lo;
}

// -------- unified prep: all fp32->bf16 conversions + weight transposes, one dispatch ----

__global__ __launch_bounds__(256) void prep_kernel(
    const float* __restrict__ x, const float* __restrict__ pemb,
    const float* __restrict__ g0w1, const float* __restrict__ g0w2,
    const float* __restrict__ gw1, const float* __restrict__ gw2,
    const float* __restrict__ wp, const float* __restrict__ wpr1, const float* __restrict__ wpr2,
    unsigned short* __restrict__ xb, unsigned short* __restrict__ pembbf,
    unsigned short* __restrict__ w10t, unsigned short* __restrict__ w20t,
    unsigned short* __restrict__ w1t, unsigned short* __restrict__ w2t,
    unsigned short* __restrict__ wpt, unsigned short* __restrict__ wpr1t,
    unsigned short* __restrict__ wpr2t, int N, int B)
{
    const long long sz0 = (long long)N * 80;
    const long long sz1 = (long long)B * 480;
    const long long szw10 = 256 * 128, szw20 = 256 * 256;
    const long long szw1 = 3 * 256 * 256, szw2 = 3 * 256 * 256;
    const long long szwp = 256 * 480, szp1 = 1024 * 512, szp2 = 512 * 1024;
    const long long total = sz0 + sz1 + szw10 + szw20 + szw1 + szw2 + szwp + szp1 + szp2;
    const long long stride = (long long)gridDim.x * blockDim.x;
    for (long long idx = (long long)blockIdx.x * blockDim.x + threadIdx.x; idx < total; idx += stride) {
        long long r = idx;
        if (r < sz0) {
            int node = (int)(r / 80), f = (int)(r - (long long)node * 80);
            xb[r] = f2bf(f < F_ATOM ? x[(long long)node * F_ATOM + f] : 0.f);
            continue;
        }
        r -= sz0;
        if (r < sz1) { pembbf[r] = f2bf(pemb[r]); continue; }
        r -= sz1;
        if (r < szw10) {
            int nr = (int)(r >> 7), k = (int)(r & 127);
            w10t[r] = f2bf(k < F_ATOM ? g0w1[k * 256 + nr] : 0.f);
            continue;
        }
        r -= szw10;
        if (r < szw20) {
            int nr = (int)(r >> 8), k = (int)(r & 255);
            w20t[r] = f2bf(g0w2[k * 256 + nr]);
            continue;
        }
        r -= szw20;
        if (r < szw1) {
            int l = (int)(r >> 16); int r2 = (int)(r & 65535);
            int nr = r2 >> 8, k = r2 & 255;
            w1t[r] = f2bf(gw1[(size_t)l * 65536 + k * 256 + nr]);
            continue;
        }
        r -= szw1;
        if (r < szw2) {
            int l = (int)(r >> 16); int r2 = (int)(r & 65535);
            int nr = r2 >> 8, k = r2 & 255;
            w2t[r] = f2bf(gw2[(size_t)l * 65536 + k * 256 + nr]);
            continue;
        }
        r -= szw2;
        if (r < szwp) {
            int nr = (int)(r / 480), k = (int)(r - (long long)nr * 480);
            wpt[r] = f2bf(wp[k * 256 + nr]);
            continue;
        }
        r -= szwp;
        if (r < szp1) {
            int nr = (int)(r >> 9), k = (int)(r & 511);
            wpr1t[r] = f2bf(wpr1[k * 1024 + nr]);
            continue;
        }
        r -= szp1;
        {
            int nr = (int)(r >> 10), k = (int)(r & 1023);
            wpr2t[r] = f2bf(wpr2[k * 512 + nr]);
        }
    }
}

// ---------------- aggregation (high-occupancy standalone gathers) ----------------

__global__ __launch_bounds__(256) void agg0b_kernel(
    const unsigned short* __restrict__ xb, const int* __restrict__ offs,
    const int* __restrict__ ssrc, unsigned short* __restrict__ z0, int n) {
    int t = threadIdx.x;
    int node = blockIdx.x * 16 + (t >> 4);
    if (node >= n) return;
    int c = t & 15;
    if (c >= 10) {
        *(uint4*)(z0 + (size_t)node * 128 + c * 8) = make_uint4(0, 0, 0, 0);
        return;
    }
    const unsigned short* base = xb + (size_t)node * 80 + c * 8;
    uint4 v = *(const uint4*)base;
    float a[8];
    a[0]=blo(v.x); a[1]=bhi(v.x); a[2]=blo(v.y); a[3]=bhi(v.y);
    a[4]=blo(v.z); a[5]=bhi(v.z); a[6]=blo(v.w); a[7]=bhi(v.w);
    int s = offs[node], e2 = offs[node + 1];
    int k = s;
    for (; k + 3 < e2; k += 4) {
        uint4 u0 = *(const uint4*)(xb + (size_t)ssrc[k]     * 80 + c * 8);
        uint4 u1 = *(const uint4*)(xb + (size_t)ssrc[k + 1] * 80 + c * 8);
        uint4 u2 = *(const uint4*)(xb + (size_t)ssrc[k + 2] * 80 + c * 8);
        uint4 u3 = *(const uint4*)(xb + (size_t)ssrc[k + 3] * 80 + c * 8);
        a[0]+=blo(u0.x); a[1]+=bhi(u0.x); a[2]+=blo(u0.y); a[3]+=bhi(u0.y);
        a[4]+=blo(u0.z); a[5]+=bhi(u0.z); a[6]+=blo(u0.w); a[7]+=bhi(u0.w);
        a[0]+=blo(u1.x); a[1]+=bhi(u1.x); a[2]+=blo(u1.y); a[3]+=bhi(u1.y);
        a[4]+=blo(u1.z); a[5]+=bhi(u1.z); a[6]+=blo(u1.w); a[7]+=bhi(u1.w);
        a[0]+=blo(u2.x); a[1]+=bhi(u2.x); a[2]+=blo(u2.y); a[3]+=bhi(u2.y);
        a[4]+=blo(u2.z); a[5]+=bhi(u2.z); a[6]+=blo(u2.w); a[7]+=bhi(u2.w);
        a[0]+=blo(u3.x); a[1]+=bhi(u3.x); a[2]+=blo(u3.y); a[3]+=bhi(u3.y);
        a[4]+=blo(u3.z); a[5]+=bhi(u3.z); a[6]+=blo(u3.w); a[7]+=bhi(u3.w);
    }
    for (; k < e2; ++k) {
        uint4 u0 = *(const uint4*)(xb + (size_t)ssrc[k] * 80 + c * 8);
        a[0]+=blo(u0.x); a[1]+=bhi(u0.x); a[2]+=blo(u0.y); a[3]+=bhi(u0.y);
        a[4]+=blo(u0.z); a[5]+=bhi(u0.z); a[6]+=blo(u0.w); a[7]+=bhi(u0.w);
    }
    unsigned int o0 = (unsigned int)f2bf(a[0]) | ((unsigned int)f2bf(a[1]) << 16);
    unsigned int o1 = (unsigned int)f2bf(a[2]) | ((unsigned int)f2bf(a[3]) << 16);
    unsigned int o2 = (unsigned int)f2bf(a[4]) | ((unsigned int)f2bf(a[5]) << 16);
    unsigned int o3 = (unsigned int)f2bf(a[6]) | ((unsigned int)f2bf(a[7]) << 16);
    *(uint4*)(z0 + (size_t)node * 128 + c * 8) = make_uint4(o0, o1, o2, o3);
}

__global__ __launch_bounds__(256) void agg_bf16_kernel(
    const unsigned short* __restrict__ h, const int* __restrict__ offs,
    const int* __restrict__ ssrc, unsigned short* __restrict__ out, int n) {
    int t = threadIdx.x;
    int node = blockIdx.x * 8 + (t >> 5);
    if (node >= n) return;
    int f8 = (t & 31) * 8;
    uint4 v = *(const uint4*)(h + (size_t)node * 256 + f8);
    float a[8];
    a[0]=blo(v.x); a[1]=bhi(v.x); a[2]=blo(v.y); a[3]=bhi(v.y);
    a[4]=blo(v.z); a[5]=bhi(v.z); a[6]=blo(v.w); a[7]=bhi(v.w);
    int s = offs[node], e2 = offs[node + 1];
    int k = s;
    for (; k + 3 < e2; k += 4) {
        uint4 u0 = *(const uint4*)(h + (size_t)ssrc[k]     * 256 + f8);
        uint4 u1 = *(const uint4*)(h + (size_t)ssrc[k + 1] * 256 + f8);
        uint4 u2 = *(const uint4*)(h + (size_t)ssrc[k + 2] * 256 + f8);
        uint4 u3 = *(const uint4*)(h + (size_t)ssrc[k + 3] * 256 + f8);
        a[0]+=blo(u0.x); a[1]+=bhi(u0.x); a[2]+=blo(u0.y); a[3]+=bhi(u0.y);
        a[4]+=blo(u0.z); a[5]+=bhi(u0.z); a[6]+=blo(u0.w); a[7]+=bhi(u0.w);
        a[0]+=blo(u1.x); a[1]+=bhi(u1.x); a[2]+=blo(u1.y); a[3]+=bhi(u1.y);
        a[4]+=blo(u1.z); a[5]+=bhi(u1.z); a[6]+=blo(u1.w); a[7]+=bhi(u1.w);
        a[0]+=blo(u2.x); a[1]+=bhi(u2.x); a[2]+=blo(u2.y); a[3]+=bhi(u2.y);
        a[4]+=blo(u2.z); a[5]+=bhi(u2.z); a[6]+=blo(u2.w); a[7]+=bhi(u2.w);
        a[0]+=blo(u3.x); a[1]+=bhi(u3.x); a[2]+=blo(u3.y); a[3]+=bhi(u3.y);
        a[4]+=blo(u3.z); a[5]+=bhi(u3.z); a[6]+=blo(u3.w); a[7]+=bhi(u3.w);
    }
    for (; k < e2; ++k) {
        uint4 u0 = *(const uint4*)(h + (size_t)ssrc[k] * 256 + f8);
        a[0]+=blo(u0.x); a[1]+=bhi(u0.x); a[2]+=blo(u0.y); a[3]+=bhi(u0.y);
        a[4]+=blo(u0.z); a[5]+=bhi(u0.z); a[6]+=blo(u0.w); a[7]+=bhi(u0.w);
    }
    unsigned int o0 = (unsigned int)f2bf(a[0]) | ((unsigned int)f2bf(a[1]) << 16);
    unsigned int o1 = (unsigned int)f2bf(a[2]) | ((unsigned int)f2bf(a[3]) << 16);
    unsigned int o2 = (unsigned int)f2bf(a[4]) | ((unsigned int)f2bf(a[5]) << 16);
    unsigned int o3 = (unsigned int)f2bf(a[6]) | ((unsigned int)f2bf(a[7]) << 16);
    *(uint4*)(out + (size_t)node * 256 + f8) = make_uint4(o0, o1, o2, o3);
}

// ---------------- fused GIN dual-GEMM, 32-row tiles for occupancy ----------------
// out = epi(relu(Z@W1^T + b1) @ W2^T + b2) [+res]. Z: bf16 [M][KSH].
// Block: 32 rows x 256 cols, 256 threads (4 waves; wave wc -> cols wc*64..+64).
// 16 KB LDS -> 5+ blocks/CU; grid ~1564 blocks -> occupancy ceiling ~60-75%.
// sZ XOR-swizzle: byte_in_row ^= (row & 15) << 4 on both write and read.

template<int KSH>
__global__ __launch_bounds__(256, 5) void fused_gin(
    const unsigned short* __restrict__ Z, const unsigned short* __restrict__ W1,
    const float* __restrict__ b1, const unsigned short* __restrict__ W2,
    const float* __restrict__ b2, const float* __restrict__ bng,
    const float* __restrict__ bnb, const unsigned short* __restrict__ res,
    unsigned short* __restrict__ out, int M)
{
    constexpr int CPR = KSH / 8;    // 16B chunks per row
    constexpr int NT1 = KSH / 32;   // K-chunks in GEMM1
    __shared__ unsigned short sZ[32 * 256];
    const int T = threadIdx.x;
    const int lane = T & 63;
    const int wc = T >> 6;
    const int fr = lane & 15, hi = lane >> 4;
    const int crow = hi * 4;
    const int row0 = blockIdx.x * 32;

    // ---- stage Z tile -> sZ [32][KSH], swizzled source / linear dest ----
    #pragma unroll
    for (int i = 0; i < (32 * CPR) / 256; ++i) {
        int c = T + i * 256;
        int row = c / CPR, p = c % CPR;
        int pp = p ^ (row & 15);
        int gr = row0 + row; if (gr > M - 1) gr = M - 1;
        __builtin_amdgcn_global_load_lds(
            (const __attribute__((address_space(1))) void*)(Z + (size_t)gr * KSH + pp * 8),
            (__attribute__((address_space(3))) void*)&sZ[c * 8], 16, 0, 0);
    }
    __syncthreads();

    floatx4 acc[2][4];
    #pragma unroll
    for (int m = 0; m < 2; ++m)
        #pragma unroll
        for (int n = 0; n < 4; ++n)
            acc[m][n] = (floatx4){0.f, 0.f, 0.f, 0.f};

    // ---- GEMM1: A = sZ [32][KSH], B = W1 direct-from-global, reg double-buffered ----
    {
        short8 cur[4], nxt[4];
        #pragma unroll
        for (int n = 0; n < 4; ++n)
            cur[n] = *(const short8*)(W1 + (size_t)(wc * 64 + n * 16 + fr) * KSH + hi * 8);
        #pragma unroll
        for (int kk = 0; kk < NT1; ++kk) {
            if (kk + 1 < NT1) {
                #pragma unroll
                for (int n = 0; n < 4; ++n)
                    nxt[n] = *(const short8*)(W1 + (size_t)(wc * 64 + n * 16 + fr) * KSH + (kk + 1) * 32 + hi * 8);
            }
            short8 af[2];
            #pragma unroll
            for (int m = 0; m < 2; ++m) {
                int r = m * 16 + fr;
                int byte = r * (KSH * 2) + ((kk * 64 + hi * 16) ^ ((r & 15) << 4));
                af[m] = *(const short8*)((const char*)sZ + byte);
            }
            #pragma unroll
            for (int m = 0; m < 2; ++m)
                #pragma unroll
                for (int n = 0; n < 4; ++n)
                    acc[m][n] = __builtin_amdgcn_mfma_f32_16x16x32_bf16(af[m], cur[n], acc[m][n], 0, 0, 0);
            #pragma unroll
            for (int n = 0; n < 4; ++n) cur[n] = nxt[n];
        }
    }
    __syncthreads();

    // ---- epilogue 1: relu(acc + b1) -> bf16 -> sZ [32][256] xor layout ----
    #pragma unroll
    for (int n = 0; n < 4; ++n) {
        int col = wc * 64 + n * 16 + fr;
        float bb = b1[col];
        #pragma unroll
        for (int m = 0; m < 2; ++m) {
            #pragma unroll
            for (int j = 0; j < 4; ++j) {
                int r = m * 16 + crow + j;
                float y = fmaxf(acc[m][n][j] + bb, 0.f);
                int byte = r * 512 + ((col * 2) ^ ((r & 15) << 4));
                *(unsigned short*)((char*)sZ + byte) = f2bf(y);
            }
        }
    }
    __syncthreads();

    // ---- GEMM2: A = relu1 (sZ [32][256]), B = W2 direct-from-global ----
    #pragma unroll
    for (int m = 0; m < 2; ++m)
        #pragma unroll
        for (int n = 0; n < 4; ++n)
            acc[m][n] = (floatx4){0.f, 0.f, 0.f, 0.f};
    {
        short8 cur[4], nxt[4];
        #pragma unroll
        for (int n = 0; n < 4; ++n)
            cur[n] = *(const short8*)(W2 + (size_t)(wc * 64 + n * 16 + fr) * 256 + hi * 8);
        #pragma unroll
        for (int kk = 0; kk < 8; ++kk) {
            if (kk < 7) {
                #pragma unroll
                for (int n = 0; n < 4; ++n)
                    nxt[n] = *(const short8*)(W2 + (size_t)(wc * 64 + n * 16 + fr) * 256 + (kk + 1) * 32 + hi * 8);
            }
            short8 af[2];
            #pragma unroll
            for (int m = 0; m < 2; ++m) {
                int r = m * 16 + fr;
                int byte = r * 512 + ((kk * 64 + hi * 16) ^ ((r & 15) << 4));
                af[m] = *(const short8*)((const char*)sZ + byte);
            }
            #pragma unroll
            for (int m = 0; m < 2; ++m)
                #pragma unroll
                for (int n = 0; n < 4; ++n)
                    acc[m][n] = __builtin_amdgcn_mfma_f32_16x16x32_bf16(af[m], cur[n], acc[m][n], 0, 0, 0);
            #pragma unroll
            for (int n = 0; n < 4; ++n) cur[n] = nxt[n];
        }
    }
    __syncthreads();   // everyone done reading relu1 before overwrite

    // ---- epilogue 2: BN(acc + b2) -> relu -> bf16 -> sZ ----
    {
        const float inv = rsqrtf(1.f + 1e-5f);
        #pragma unroll
        for (int n = 0; n < 4; ++n) {
            int col = wc * 64 + n * 16 + fr;
            float bb = b2[col];
            float sc = bng[col] * inv, be = bnb[col];
            #pragma unroll
            for (int m = 0; m < 2; ++m) {
                #pragma unroll
                for (int j = 0; j < 4; ++j) {
                    int r = m * 16 + crow + j;
                    float y = (acc[m][n][j] + bb) * sc + be;
                    y = fmaxf(y, 0.f);
                    int byte = r * 512 + ((col * 2) ^ ((r & 15) << 4));
                    *(unsigned short*)((char*)sZ + byte) = f2bf(y);
                }
            }
        }
    }
    __syncthreads();

    // ---- write-out: linear, coalesced, fused residual add ----
    #pragma unroll
    for (int i = 0; i < 4; ++i) {
        int c = T + i * 256;
        int row = c >> 5, slot = c & 31;
        int gr = row0 + row;
        if (gr >= M) continue;
        int byte = row * 512 + ((slot * 16) ^ ((row & 15) << 4));
        short8 v = *(const short8*)((const char*)sZ + byte);
        if (res) {
            short8 rv = *(const short8*)(res + (size_t)gr * 256 + slot * 8);
            #pragma unroll
            for (int e = 0; e < 8; ++e) {
                float f = bf2f((unsigned short)v[e]) + bf2f((unsigned short)rv[e]);
                v[e] = (short)f2bf(f);
            }
        }
        *(short8*)(out + (size_t)gr * 256 + slot * 8) = v;
    }
}

// ---------------- generic bf16 MFMA GEMM (small shapes: protein, MLP) ----------------

__global__ __launch_bounds__(256) void mfma_gemm(
    const unsigned short* __restrict__ A, const unsigned short* __restrict__ Bt,
    const float* __restrict__ bias, const float* __restrict__ bng,
    const float* __restrict__ bnb, const unsigned short* __restrict__ res,
    unsigned short* __restrict__ out, int M, int K, int NC, int flags)
{
    __shared__ unsigned short sA[2][128 * 32];
    __shared__ unsigned short sB[2][128 * 32];
    const int T = threadIdx.x;
    const int lane = T & 63;
    const int w = T >> 6, wr = w >> 1, wc = w & 1;
    const int row0 = blockIdx.x * 128;
    const int col0 = blockIdx.y * 128;
    const int nt = K >> 5;

    floatx4 acc[4][4];
    #pragma unroll
    for (int m = 0; m < 4; ++m)
        #pragma unroll
        for (int n = 0; n < 4; ++n)
            acc[m][n] = (floatx4){0.f, 0.f, 0.f, 0.f};

    auto stage = [&](int buf, int k0) {
        #pragma unroll
        for (int it = 0; it < 2; ++it) {
            int c = T + it * 256;
            int r = c >> 2, p = c & 3;
            int gr = row0 + r; if (gr > M - 1) gr = M - 1;
            const unsigned short* gA = A + (size_t)gr * K + k0 + p * 8;
            __builtin_amdgcn_global_load_lds(
                (const __attribute__((address_space(1))) void*)gA,
                (__attribute__((address_space(3))) void*)&sA[buf][c * 8], 16, 0, 0);
            const unsigned short* gB = Bt + (size_t)(col0 + r) * K + k0 + p * 8;
            __builtin_amdgcn_global_load_lds(
                (const __attribute__((address_space(1))) void*)gB,
                (__attribute__((address_space(3))) void*)&sB[buf][c * 8], 16, 0, 0);
        }
    };

    auto compute = [&](int buf) {
        const int fr = lane & 15;
        const int kh = (lane >> 4) * 8;
        short8 af[4], bv[4];
        #pragma unroll
        for (int m = 0; m < 4; ++m)
            af[m] = *(const short8*)&sA[buf][(wr * 64 + m * 16 + fr) * 32 + kh];
        #pragma unroll
        for (int n = 0; n < 4; ++n)
            bv[n] = *(const short8*)&sB[buf][(wc * 64 + n * 16 + fr) * 32 + kh];
        #pragma unroll
        for (int m = 0; m < 4; ++m)
            #pragma unroll
            for (int n = 0; n < 4; ++n)
                acc[m][n] = __builtin_amdgcn_mfma_f32_16x16x32_bf16(af[m], bv[n], acc[m][n], 0, 0, 0);
    };

    stage(0, 0);
    __syncthreads();
    int cur = 0;
    for (int t = 0; t < nt - 1; ++t) {
        stage(cur ^ 1, (t + 1) * 32);
        compute(cur);
        __syncthreads();
        cur ^= 1;
    }
    compute(cur);

    const int crow = (lane >> 4) * 4;
    const int ccol = lane & 15;
    const float inv = rsqrtf(1.f + 1e-5f);
    #pragma unroll
    for (int n = 0; n < 4; ++n) {
        int col = col0 + wc * 64 + n * 16 + ccol;
        float bb = bias ? bias[col] : 0.f;
        float sc = 1.f, be = 0.f;
        if (flags & FLAG_BN) { sc = bng[col] * inv; be = bnb[col]; }
        #pragma unroll
        for (int m = 0; m < 4; ++m) {
            #pragma unroll
            for (int j = 0; j < 4; ++j) {
                int r = row0 + wr * 64 + m * 16 + crow + j;
                if (r >= M) continue;
                float y = acc[m][n][j] + bb;
                if (flags & FLAG_BN) y = y * sc + be;
                if (flags & FLAG_RELU) y = fmaxf(y, 0.f);
                if (flags & FLAG_RES) y += bf2f(res[(size_t)r * NC + col]);
                out[(size_t)r * NC + col] = f2bf(y);
            }
        }
    }
}

// ---------------- pooling, LN, final dot ----------------

__global__ void pool_kernel(const unsigned short* __restrict__ h, const int* __restrict__ goffs,
                            unsigned short* __restrict__ out, int ldout) {
    int g = blockIdx.x;
    int f = threadIdx.x;
    int s = goffs[g], e = goffs[g + 1];
    float acc = 0.f;
    for (int i = s; i < e; ++i) acc += bf2f(h[(size_t)i * 256 + f]);
    out[(size_t)g * ldout + f] = f2bf(acc);
}

__global__ void ln_relu_kernel(const unsigned short* __restrict__ p, const float* __restrict__ g,
                               const float* __restrict__ b, unsigned short* __restrict__ out, int ldout) {
    int row = blockIdx.x;
    int t = threadIdx.x; // 256
    float v = bf2f(p[(size_t)row * 256 + t]);
    float s1 = v, s2 = v * v;
    #pragma unroll
    for (int o = 32; o > 0; o >>= 1) { s1 += __shfl_xor(s1, o); s2 += __shfl_xor(s2, o); }
    __shared__ float as1[4], as2[4];
    int w = t >> 6, lane = t & 63;
    if (lane == 0) { as1[w] = s1; as2[w] = s2; }
    __syncthreads();
    float tot1 = as1[0] + as1[1] + as1[2] + as1[3];
    float tot2 = as2[0] + as2[1] + as2[2] + as2[3];
    float mean = tot1 * (1.f / 256.f);
    float var = tot2 * (1.f / 256.f) - mean * mean;
    float y = (v - mean) * rsqrtf(var + 1e-5f) * g[t] + b[t];
    out[(size_t)row * ldout + t] = f2bf(fmaxf(y, 0.f));
}

__global__ void pred3_kernel(const unsigned short* __restrict__ h2, const float* __restrict__ w,
                             const float* __restrict__ b, float* __restrict__ out, int B) {
    int row = blockIdx.x * 4 + (threadIdx.x >> 6);
    int lane = threadIdx.x & 63;
    if (row >= B) return;
    float acc = 0.f;
    #pragma unroll
    for (int k = 0; k < 512; k += 64) acc += bf2f(h2[(size_t)row * 512 + k + lane]) * w[k + lane];
    #pragma unroll
    for (int o = 32; o > 0; o >>= 1) acc += __shfl_xor(acc, o);
    if (lane == 0) out[row] = acc + b[0];
}

// ---------------- host ----------------

extern "C" void kernel_launch(void* const* d_in, const int* in_sizes, int n_in,
                              void* d_out, int out_size, void* d_ws, size_t ws_size,
                              hipStream_t stream) {
    const float* x    = (const float*)d_in[0];
    const int*   ei   = (const int*)d_in[1];
    const int*   batch= (const int*)d_in[2];
    const float* pemb = (const float*)d_in[3];
    const float* g0w1 = (const float*)d_in[4];
    const float* g0b1 = (const float*)d_in[5];
    const float* g0w2 = (const float*)d_in[6];
    const float* g0b2 = (const float*)d_in[7];
    const float* g0g  = (const float*)d_in[8];
    const float* g0be = (const float*)d_in[9];
    const float* gw1  = (const float*)d_in[10];
    const float* gb1  = (const float*)d_in[11];
    const float* gw2  = (const float*)d_in[12];
    const float* gb2  = (const float*)d_in[13];
    const float* gg   = (const float*)d_in[14];
    const float* gbe  = (const float*)d_in[15];
    const float* wp   = (const float*)d_in[16];
    const float* bp   = (const float*)d_in[17];
    const float* lng  = (const float*)d_in[18];
    const float* lnb  = (const float*)d_in[19];
    const float* wpr1 = (const float*)d_in[20];
    const float* bpr1 = (const float*)d_in[21];
    const float* wpr2 = (const float*)d_in[22];
    const float* bpr2 = (const float*)d_in[23];
    const float* wpr3 = (const float*)d_in[24];
    const float* bpr3 = (const float*)d_in[25];

    int N = in_sizes[0] / F_ATOM;
    int E = in_sizes[1] / 2;
    int B = in_sizes[3] / 480;

    char* wsp = (char*)d_ws;
    auto carve = [&](size_t bytes) {
        void* p = (void*)wsp;
        wsp += (bytes + 255) & ~(size_t)255;
        return p;
    };
    int* offs   = (int*)carve((size_t)(N + 1) * 4);
    int* cursor = (int*)carve((size_t)N * 4);
    int* ssrc   = (int*)carve((size_t)E * 4);
    int* goffs  = (int*)carve((size_t)(B + 1) * 4);
    unsigned short* xb   = (unsigned short*)carve((size_t)N * 80 * 2);
    unsigned short* z0   = (unsigned short*)carve((size_t)N * 128 * 2);
    unsigned short* hbuf = (unsigned short*)carve((size_t)N * 256 * 2);
    unsigned short* tbuf = (unsigned short*)carve((size_t)N * 256 * 2);
    unsigned short* zbuf = (unsigned short*)carve((size_t)N * 256 * 2);
    unsigned short* pembbf = (unsigned short*)carve((size_t)B * 480 * 2);
    unsigned short* ptmp = (unsigned short*)carve((size_t)B * 256 * 2);
    unsigned short* cat  = (unsigned short*)carve((size_t)B * 512 * 2);
    unsigned short* h1   = (unsigned short*)carve((size_t)B * 1024 * 2);
    unsigned short* h2   = (unsigned short*)carve((size_t)B * 512 * 2);
    unsigned short* w10t = (unsigned short*)carve((size_t)256 * 128 * 2);
    unsigned short* w20t = (unsigned short*)carve((size_t)256 * 256 * 2);
    unsigned short* w1t  = (unsigned short*)carve((size_t)3 * 256 * 256 * 2);
    unsigned short* w2t  = (unsigned short*)carve((size_t)3 * 256 * 256 * 2);
    unsigned short* wpt  = (unsigned short*)carve((size_t)256 * 480 * 2);
    unsigned short* wpr1t= (unsigned short*)carve((size_t)1024 * 512 * 2);
    unsigned short* wpr2t= (unsigned short*)carve((size_t)512 * 1024 * 2);

    const int* srcp = ei;
    const int* dstp = ei + E;

    // CSR by dst
    hipMemsetAsync(cursor, 0, (size_t)N * 4, stream);
    count_kernel<<<(E + 255) / 256, 256, 0, stream>>>(dstp, cursor, E);
    scan_kernel<<<1, 1024, 0, stream>>>(cursor, offs, N);
    hipMemsetAsync(cursor, 0, (size_t)N * 4, stream);
    fill_kernel<<<(E + 255) / 256, 256, 0, stream>>>(srcp, dstp, offs, cursor, ssrc, E);
    graph_bounds_kernel<<<(B + 256) / 256, 256, 0, stream>>>(batch, goffs, N, B);

    // unified prep (all converts + transposes, one dispatch)
    prep_kernel<<<2048, 256, 0, stream>>>(x, pemb, g0w1, g0w2, gw1, gw2, wp, wpr1, wpr2,
                                          xb, pembbf, w10t, w20t, w1t, w2t, wpt, wpr1t, wpr2t,
                                          N, B);

    int rbN = (N + 31) / 32;

    // layer 0 (70 -> 256)
    agg0b_kernel<<<(N + 15) / 16, 256, 0, stream>>>(xb, offs, ssrc, z0, N);
    fused_gin<128><<<rbN, 256, 0, stream>>>(z0, w10t, g0b1, w20t, g0b2, g0g, g0be,
                                            nullptr, hbuf, N);

    // layers 1..3 with residual
    unsigned short* H = hbuf; unsigned short* T2 = tbuf;
    for (int i = 0; i < 3; ++i) {
        agg_bf16_kernel<<<(N + 7) / 8, 256, 0, stream>>>(H, offs, ssrc, zbuf, N);
        fused_gin<256><<<rbN, 256, 0, stream>>>(zbuf, w1t + (size_t)i * 65536, gb1 + i * 256,
                                                w2t + (size_t)i * 65536, gb2 + i * 256,
                                                gg + i * 256, gbe + i * 256, H, T2, N);
        unsigned short* tmp = H; H = T2; T2 = tmp;
    }

    // pool -> cat[:, 0:256]
    pool_kernel<<<B, 256, 0, stream>>>(H, goffs, cat, 512);

    // protein projector -> cat[:, 256:512]
    mfma_gemm<<<dim3((B + 127) / 128, 2), 256, 0, stream>>>(pembbf, wpt, bp, nullptr, nullptr, nullptr,
                                                            ptmp, B, 480, 256, 0);
    ln_relu_kernel<<<B, 256, 0, stream>>>(ptmp, lng, lnb, cat + 256, 512);

    // predictor MLP
    mfma_gemm<<<dim3((B + 127) / 128, 8), 256, 0, stream>>>(cat, wpr1t, bpr1, nullptr, nullptr, nullptr,
                                                            h1, B, 512, 1024, FLAG_RELU);
    mfma_gemm<<<dim3((B + 127) / 128, 4), 256, 0, stream>>>(h1, wpr2t, bpr2, nullptr, nullptr, nullptr,
                                                            h2, B, 1024, 512, FLAG_RELU);
    pred3_kernel<<<(B + 3) / 4, 256, 0, stream>>>(h2, wpr3, bpr3, (float*)d_out, B);
}

// Round 9
// 575.349 us; speedup vs baseline: 1.0051x; 1.0051x over previous
//
#include <hip/hip_runtime.h>

#define F_ATOM 70

#define FLAG_RELU 1
#define FLAG_BN   2
#define FLAG_RES  4

typedef __attribute__((ext_vector_type(8))) short short8;
typedef __attribute__((ext_vector_type(4))) float floatx4;

__device__ __forceinline__ float bf2f(unsigned short u) {
    union { unsigned int i; float f; } x; x.i = (unsigned int)u << 16; return x.f;
}
__device__ __forceinline__ unsigned short f2bf(float f) {
    union { float f; unsigned int i; } x; x.f = f;
    unsigned int r = x.i + 0x7fffu + ((x.i >> 16) & 1u);
    return (unsigned short)(r >> 16);
}
__device__ __forceinline__ float blo(unsigned int u){ union{unsigned int a; float f;}x; x.a=u<<16; return x.f; }
__device__ __forceinline__ float bhi(unsigned int u){ union{unsigned int a; float f;}x; x.a=u&0xffff0000u; return x.f; }

// ---------------- CSR build ----------------

__global__ void count_kernel(const int* __restrict__ dst, int* __restrict__ cnt, int E) {
    int i = blockIdx.x * blockDim.x + threadIdx.x;
    if (i < E) atomicAdd(&cnt[dst[i]], 1);
}

// 3-kernel parallel exclusive scan over cnt[0..n) -> offs[0..n]
__global__ void scan_sum_kernel(const int* __restrict__ cnt, int* __restrict__ partial, int n) {
    int t = threadIdx.x;
    int base = blockIdx.x * 1024 + t * 4;
    int v = 0;
    #pragma unroll
    for (int i = 0; i < 4; ++i) if (base + i < n) v += cnt[base + i];
    #pragma unroll
    for (int o = 32; o > 0; o >>= 1) v += __shfl_down(v, o);
    __shared__ int ws[4];
    if ((t & 63) == 0) ws[t >> 6] = v;
    __syncthreads();
    if (t == 0) partial[blockIdx.x] = ws[0] + ws[1] + ws[2] + ws[3];
}

__global__ void scan_part_kernel(int* __restrict__ partial, int nb) {
    int t = threadIdx.x, lane = t & 63, w = t >> 6;
    int v = (t < nb) ? partial[t] : 0;
    int s = v;
    #pragma unroll
    for (int o = 1; o < 64; o <<= 1) { int x = __shfl_up(s, o); if (lane >= o) s += x; }
    __shared__ int wsum[16];
    if (lane == 63) wsum[w] = s;
    __syncthreads();
    int woff = 0;
    #pragma unroll
    for (int i = 0; i < 16; ++i) woff += (i < w) ? wsum[i] : 0;
    if (t < nb) partial[t] = woff + s - v;
    if (t == 1023) partial[nb] = woff + s;
}

__global__ void scan_apply_kernel(const int* __restrict__ cnt, const int* __restrict__ partial,
                                  int* __restrict__ offs, int n, int nb) {
    int t = threadIdx.x;
    int base = blockIdx.x * 1024 + t * 4;
    int v[4];
    #pragma unroll
    for (int i = 0; i < 4; ++i) v[i] = (base + i < n) ? cnt[base + i] : 0;
    int tsum = v[0] + v[1] + v[2] + v[3];
    int lane = t & 63, w = t >> 6;
    int s = tsum;
    #pragma unroll
    for (int o = 1; o < 64; o <<= 1) { int x = __shfl_up(s, o); if (lane >= o) s += x; }
    __shared__ int wsum[4];
    if (lane == 63) wsum[w] = s;
    __syncthreads();
    int woff = 0;
    #pragma unroll
    for (int i = 0; i < 4; ++i) woff += (i < w) ? wsum[i] : 0;
    int run = partial[blockIdx.x] + woff + s - tsum;
    #pragma unroll
    for (int i = 0; i < 4; ++i) { if (base + i < n) offs[base + i] = run; run += v[i]; }
    if (blockIdx.x == 0 && t == 0) offs[n] = partial[nb];
}

// fill via atomicSub on counts (cursor holds per-node counts after count_kernel; scan only reads)
__global__ void fill_kernel(const int* __restrict__ src, const int* __restrict__ dst,
                            const int* __restrict__ offs, int* __restrict__ cursor,
                            int* __restrict__ ssrc, int E) {
    int i = blockIdx.x * blockDim.x + threadIdx.x;
    if (i < E) {
        int d = dst[i];
        int pos = atomicSub(&cursor[d], 1);
        ssrc[offs[d] + pos - 1] = src[i];
    }
}

__global__ void graph_bounds_kernel(const int* __restrict__ batch, int* __restrict__ goffs,
                                    int N, int B) {
    int g = blockIdx.x * blockDim.x + threadIdx.x;
    if (g > B) return;
    int lo = 0, hi = N;
    while (lo < hi) {
        int mid = (lo + hi) >> 1;
        if (batch[mid] < g) lo = mid + 1; else hi = mid;
    }
    goffs[g] = lo;
}

// -------- unified prep: all fp32->bf16 conversions + weight transposes, one dispatch ----

__global__ __launch_bounds__(256) void prep_kernel(
    const float* __restrict__ x, const float* __restrict__ pemb,
    const float* __restrict__ g0w1, const float* __restrict__ g0w2,
    const float* __restrict__ gw1, const float* __restrict__ gw2,
    const float* __restrict__ wp, const float* __restrict__ wpr1, const float* __restrict__ wpr2,
    unsigned short* __restrict__ xb, unsigned short* __restrict__ pembbf,
    unsigned short* __restrict__ w10t, unsigned short* __restrict__ w20t,
    unsigned short* __restrict__ w1t, unsigned short* __restrict__ w2t,
    unsigned short* __restrict__ wpt, unsigned short* __restrict__ wpr1t,
    unsigned short* __restrict__ wpr2t, int N, int B)
{
    const long long sz0 = (long long)N * 80;
    const long long sz1 = (long long)B * 480;
    const long long szw10 = 256 * 128, szw20 = 256 * 256;
    const long long szw1 = 3 * 256 * 256, szw2 = 3 * 256 * 256;
    const long long szwp = 256 * 480, szp1 = 1024 * 512, szp2 = 512 * 1024;
    const long long total = sz0 + sz1 + szw10 + szw20 + szw1 + szw2 + szwp + szp1 + szp2;
    const long long stride = (long long)gridDim.x * blockDim.x;
    for (long long idx = (long long)blockIdx.x * blockDim.x + threadIdx.x; idx < total; idx += stride) {
        long long r = idx;
        if (r < sz0) {
            int node = (int)(r / 80), f = (int)(r - (long long)node * 80);
            xb[r] = f2bf(f < F_ATOM ? x[(long long)node * F_ATOM + f] : 0.f);
            continue;
        }
        r -= sz0;
        if (r < sz1) { pembbf[r] = f2bf(pemb[r]); continue; }
        r -= sz1;
        if (r < szw10) {
            int nr = (int)(r >> 7), k = (int)(r & 127);
            w10t[r] = f2bf(k < F_ATOM ? g0w1[k * 256 + nr] : 0.f);
            continue;
        }
        r -= szw10;
        if (r < szw20) {
            int nr = (int)(r >> 8), k = (int)(r & 255);
            w20t[r] = f2bf(g0w2[k * 256 + nr]);
            continue;
        }
        r -= szw20;
        if (r < szw1) {
            int l = (int)(r >> 16); int r2 = (int)(r & 65535);
            int nr = r2 >> 8, k = r2 & 255;
            w1t[r] = f2bf(gw1[(size_t)l * 65536 + k * 256 + nr]);
            continue;
        }
        r -= szw1;
        if (r < szw2) {
            int l = (int)(r >> 16); int r2 = (int)(r & 65535);
            int nr = r2 >> 8, k = r2 & 255;
            w2t[r] = f2bf(gw2[(size_t)l * 65536 + k * 256 + nr]);
            continue;
        }
        r -= szw2;
        if (r < szwp) {
            int nr = (int)(r / 480), k = (int)(r - (long long)nr * 480);
            wpt[r] = f2bf(wp[k * 256 + nr]);
            continue;
        }
        r -= szwp;
        if (r < szp1) {
            int nr = (int)(r >> 9), k = (int)(r & 511);
            wpr1t[r] = f2bf(wpr1[k * 1024 + nr]);
            continue;
        }
        r -= szp1;
        {
            int nr = (int)(r >> 10), k = (int)(r & 1023);
            wpr2t[r] = f2bf(wpr2[k * 512 + nr]);
        }
    }
}

// ---------------- aggregation (high-occupancy standalone gathers, 8-deep unroll) -------

__global__ __launch_bounds__(256) void agg0b_kernel(
    const unsigned short* __restrict__ xb, const int* __restrict__ offs,
    const int* __restrict__ ssrc, unsigned short* __restrict__ z0, int n) {
    int t = threadIdx.x;
    int node = blockIdx.x * 16 + (t >> 4);
    if (node >= n) return;
    int c = t & 15;
    if (c >= 10) {
        *(uint4*)(z0 + (size_t)node * 128 + c * 8) = make_uint4(0, 0, 0, 0);
        return;
    }
    float a[8];
    {
        uint4 v = *(const uint4*)(xb + (size_t)node * 80 + c * 8);
        a[0]=blo(v.x); a[1]=bhi(v.x); a[2]=blo(v.y); a[3]=bhi(v.y);
        a[4]=blo(v.z); a[5]=bhi(v.z); a[6]=blo(v.w); a[7]=bhi(v.w);
    }
    int s = offs[node], e2 = offs[node + 1];
    int k = s;
    for (; k + 7 < e2; k += 8) {
        uint4 u[8];
        #pragma unroll
        for (int q = 0; q < 8; ++q)
            u[q] = *(const uint4*)(xb + (size_t)ssrc[k + q] * 80 + c * 8);
        #pragma unroll
        for (int q = 0; q < 8; ++q) {
            a[0]+=blo(u[q].x); a[1]+=bhi(u[q].x); a[2]+=blo(u[q].y); a[3]+=bhi(u[q].y);
            a[4]+=blo(u[q].z); a[5]+=bhi(u[q].z); a[6]+=blo(u[q].w); a[7]+=bhi(u[q].w);
        }
    }
    for (; k + 1 < e2; k += 2) {
        uint4 u0 = *(const uint4*)(xb + (size_t)ssrc[k]     * 80 + c * 8);
        uint4 u1 = *(const uint4*)(xb + (size_t)ssrc[k + 1] * 80 + c * 8);
        a[0]+=blo(u0.x); a[1]+=bhi(u0.x); a[2]+=blo(u0.y); a[3]+=bhi(u0.y);
        a[4]+=blo(u0.z); a[5]+=bhi(u0.z); a[6]+=blo(u0.w); a[7]+=bhi(u0.w);
        a[0]+=blo(u1.x); a[1]+=bhi(u1.x); a[2]+=blo(u1.y); a[3]+=bhi(u1.y);
        a[4]+=blo(u1.z); a[5]+=bhi(u1.z); a[6]+=blo(u1.w); a[7]+=bhi(u1.w);
    }
    if (k < e2) {
        uint4 u0 = *(const uint4*)(xb + (size_t)ssrc[k] * 80 + c * 8);
        a[0]+=blo(u0.x); a[1]+=bhi(u0.x); a[2]+=blo(u0.y); a[3]+=bhi(u0.y);
        a[4]+=blo(u0.z); a[5]+=bhi(u0.z); a[6]+=blo(u0.w); a[7]+=bhi(u0.w);
    }
    unsigned int o0 = (unsigned int)f2bf(a[0]) | ((unsigned int)f2bf(a[1]) << 16);
    unsigned int o1 = (unsigned int)f2bf(a[2]) | ((unsigned int)f2bf(a[3]) << 16);
    unsigned int o2 = (unsigned int)f2bf(a[4]) | ((unsigned int)f2bf(a[5]) << 16);
    unsigned int o3 = (unsigned int)f2bf(a[6]) | ((unsigned int)f2bf(a[7]) << 16);
    *(uint4*)(z0 + (size_t)node * 128 + c * 8) = make_uint4(o0, o1, o2, o3);
}

__global__ __launch_bounds__(256) void agg_bf16_kernel(
    const unsigned short* __restrict__ h, const int* __restrict__ offs,
    const int* __restrict__ ssrc, unsigned short* __restrict__ out, int n) {
    int t = threadIdx.x;
    int node = blockIdx.x * 8 + (t >> 5);
    if (node >= n) return;
    int f8 = (t & 31) * 8;
    float a[8];
    {
        uint4 v = *(const uint4*)(h + (size_t)node * 256 + f8);
        a[0]=blo(v.x); a[1]=bhi(v.x); a[2]=blo(v.y); a[3]=bhi(v.y);
        a[4]=blo(v.z); a[5]=bhi(v.z); a[6]=blo(v.w); a[7]=bhi(v.w);
    }
    int s = offs[node], e2 = offs[node + 1];
    int k = s;
    for (; k + 7 < e2; k += 8) {
        uint4 u[8];
        #pragma unroll
        for (int q = 0; q < 8; ++q)
            u[q] = *(const uint4*)(h + (size_t)ssrc[k + q] * 256 + f8);
        #pragma unroll
        for (int q = 0; q < 8; ++q) {
            a[0]+=blo(u[q].x); a[1]+=bhi(u[q].x); a[2]+=blo(u[q].y); a[3]+=bhi(u[q].y);
            a[4]+=blo(u[q].z); a[5]+=bhi(u[q].z); a[6]+=blo(u[q].w); a[7]+=bhi(u[q].w);
        }
    }
    for (; k + 1 < e2; k += 2) {
        uint4 u0 = *(const uint4*)(h + (size_t)ssrc[k]     * 256 + f8);
        uint4 u1 = *(const uint4*)(h + (size_t)ssrc[k + 1] * 256 + f8);
        a[0]+=blo(u0.x); a[1]+=bhi(u0.x); a[2]+=blo(u0.y); a[3]+=bhi(u0.y);
        a[4]+=blo(u0.z); a[5]+=bhi(u0.z); a[6]+=blo(u0.w); a[7]+=bhi(u0.w);
        a[0]+=blo(u1.x); a[1]+=bhi(u1.x); a[2]+=blo(u1.y); a[3]+=bhi(u1.y);
        a[4]+=blo(u1.z); a[5]+=bhi(u1.z); a[6]+=blo(u1.w); a[7]+=bhi(u1.w);
    }
    if (k < e2) {
        uint4 u0 = *(const uint4*)(h + (size_t)ssrc[k] * 256 + f8);
        a[0]+=blo(u0.x); a[1]+=bhi(u0.x); a[2]+=blo(u0.y); a[3]+=bhi(u0.y);
        a[4]+=blo(u0.z); a[5]+=bhi(u0.z); a[6]+=blo(u0.w); a[7]+=bhi(u0.w);
    }
    unsigned int o0 = (unsigned int)f2bf(a[0]) | ((unsigned int)f2bf(a[1]) << 16);
    unsigned int o1 = (unsigned int)f2bf(a[2]) | ((unsigned int)f2bf(a[3]) << 16);
    unsigned int o2 = (unsigned int)f2bf(a[4]) | ((unsigned int)f2bf(a[5]) << 16);
    unsigned int o3 = (unsigned int)f2bf(a[6]) | ((unsigned int)f2bf(a[7]) << 16);
    *(uint4*)(out + (size_t)node * 256 + f8) = make_uint4(o0, o1, o2, o3);
}

// ---------------- fused GIN dual-GEMM (R7-verified 64-row config + res prefetch) -------
// out = epi(relu(Z@W1^T + b1) @ W2^T + b2) [+res]. Z: bf16 [M][KSH].
// Block: 64 rows x 256 cols, 256 threads (4 waves; wave wc -> cols wc*64..+64).
// sZ XOR-swizzle: byte_in_row ^= (row & 15) << 4 on both write and read.
// res prefetched into registers at kernel start (hides HBM latency under compute).

template<int KSH>
__global__ __launch_bounds__(256, 4) void fused_gin(
    const unsigned short* __restrict__ Z, const unsigned short* __restrict__ W1,
    const float* __restrict__ b1, const unsigned short* __restrict__ W2,
    const float* __restrict__ b2, const float* __restrict__ bng,
    const float* __restrict__ bnb, const unsigned short* __restrict__ res,
    unsigned short* __restrict__ out, int M)
{
    constexpr int CPR = KSH / 8;    // 16B chunks per row
    constexpr int NT1 = KSH / 32;   // K-chunks in GEMM1
    __shared__ unsigned short sZ[64 * 256];
    const int T = threadIdx.x;
    const int lane = T & 63;
    const int wc = T >> 6;
    const int fr = lane & 15, hi = lane >> 4;
    const int crow = hi * 4;
    const int row0 = blockIdx.x * 64;

    // ---- res prefetch (issued before everything; consumed at writeout) ----
    short8 resv[8];
    if (res) {
        #pragma unroll
        for (int i = 0; i < 8; ++i) {
            int c = T + i * 256;
            int row = c >> 5, slot = c & 31;
            int gr = row0 + row; if (gr > M - 1) gr = M - 1;
            resv[i] = *(const short8*)(res + (size_t)gr * 256 + slot * 8);
        }
    }

    // ---- stage Z tile -> sZ [64][KSH], swizzled source / linear dest ----
    #pragma unroll
    for (int i = 0; i < (64 * CPR) / 256; ++i) {
        int c = T + i * 256;
        int row = c / CPR, p = c % CPR;
        int pp = p ^ (row & 15);
        int gr = row0 + row; if (gr > M - 1) gr = M - 1;
        __builtin_amdgcn_global_load_lds(
            (const __attribute__((address_space(1))) void*)(Z + (size_t)gr * KSH + pp * 8),
            (__attribute__((address_space(3))) void*)&sZ[c * 8], 16, 0, 0);
    }
    __syncthreads();

    floatx4 acc[4][4];
    #pragma unroll
    for (int m = 0; m < 4; ++m)
        #pragma unroll
        for (int n = 0; n < 4; ++n)
            acc[m][n] = (floatx4){0.f, 0.f, 0.f, 0.f};

    // ---- GEMM1: A = sZ [64][KSH], B = W1 direct-from-global, reg double-buffered ----
    {
        short8 cur[4], nxt[4];
        #pragma unroll
        for (int n = 0; n < 4; ++n)
            cur[n] = *(const short8*)(W1 + (size_t)(wc * 64 + n * 16 + fr) * KSH + hi * 8);
        #pragma unroll
        for (int kk = 0; kk < NT1; ++kk) {
            if (kk + 1 < NT1) {
                #pragma unroll
                for (int n = 0; n < 4; ++n)
                    nxt[n] = *(const short8*)(W1 + (size_t)(wc * 64 + n * 16 + fr) * KSH + (kk + 1) * 32 + hi * 8);
            }
            short8 af[4];
            #pragma unroll
            for (int m = 0; m < 4; ++m) {
                int r = m * 16 + fr;
                int byte = r * (KSH * 2) + ((kk * 64 + hi * 16) ^ ((r & 15) << 4));
                af[m] = *(const short8*)((const char*)sZ + byte);
            }
            #pragma unroll
            for (int m = 0; m < 4; ++m)
                #pragma unroll
                for (int n = 0; n < 4; ++n)
                    acc[m][n] = __builtin_amdgcn_mfma_f32_16x16x32_bf16(af[m], cur[n], acc[m][n], 0, 0, 0);
            #pragma unroll
            for (int n = 0; n < 4; ++n) cur[n] = nxt[n];
        }
    }
    __syncthreads();

    // ---- epilogue 1: relu(acc + b1) -> bf16 -> sZ [64][256] xor layout ----
    #pragma unroll
    for (int n = 0; n < 4; ++n) {
        int col = wc * 64 + n * 16 + fr;
        float bb = b1[col];
        #pragma unroll
        for (int m = 0; m < 4; ++m) {
            #pragma unroll
            for (int j = 0; j < 4; ++j) {
                int r = m * 16 + crow + j;
                float y = fmaxf(acc[m][n][j] + bb, 0.f);
                int byte = r * 512 + ((col * 2) ^ ((r & 15) << 4));
                *(unsigned short*)((char*)sZ + byte) = f2bf(y);
            }
        }
    }
    __syncthreads();

    // ---- GEMM2: A = relu1 (sZ [64][256]), B = W2 direct-from-global ----
    #pragma unroll
    for (int m = 0; m < 4; ++m)
        #pragma unroll
        for (int n = 0; n < 4; ++n)
            acc[m][n] = (floatx4){0.f, 0.f, 0.f, 0.f};
    {
        short8 cur[4], nxt[4];
        #pragma unroll
        for (int n = 0; n < 4; ++n)
            cur[n] = *(const short8*)(W2 + (size_t)(wc * 64 + n * 16 + fr) * 256 + hi * 8);
        #pragma unroll
        for (int kk = 0; kk < 8; ++kk) {
            if (kk < 7) {
                #pragma unroll
                for (int n = 0; n < 4; ++n)
                    nxt[n] = *(const short8*)(W2 + (size_t)(wc * 64 + n * 16 + fr) * 256 + (kk + 1) * 32 + hi * 8);
            }
            short8 af[4];
            #pragma unroll
            for (int m = 0; m < 4; ++m) {
                int r = m * 16 + fr;
                int byte = r * 512 + ((kk * 64 + hi * 16) ^ ((r & 15) << 4));
                af[m] = *(const short8*)((const char*)sZ + byte);
            }
            #pragma unroll
            for (int m = 0; m < 4; ++m)
                #pragma unroll
                for (int n = 0; n < 4; ++n)
                    acc[m][n] = __builtin_amdgcn_mfma_f32_16x16x32_bf16(af[m], cur[n], acc[m][n], 0, 0, 0);
            #pragma unroll
            for (int n = 0; n < 4; ++n) cur[n] = nxt[n];
        }
    }
    __syncthreads();   // everyone done reading relu1 before overwrite

    // ---- epilogue 2: BN(acc + b2) -> relu -> bf16 -> sZ ----
    {
        const float inv = rsqrtf(1.f + 1e-5f);
        #pragma unroll
        for (int n = 0; n < 4; ++n) {
            int col = wc * 64 + n * 16 + fr;
            float bb = b2[col];
            float sc = bng[col] * inv, be = bnb[col];
            #pragma unroll
            for (int m = 0; m < 4; ++m) {
                #pragma unroll
                for (int j = 0; j < 4; ++j) {
                    int r = m * 16 + crow + j;
                    float y = (acc[m][n][j] + bb) * sc + be;
                    y = fmaxf(y, 0.f);
                    int byte = r * 512 + ((col * 2) ^ ((r & 15) << 4));
                    *(unsigned short*)((char*)sZ + byte) = f2bf(y);
                }
            }
        }
    }
    __syncthreads();

    // ---- write-out: linear, coalesced, residual from prefetched registers ----
    #pragma unroll
    for (int i = 0; i < 8; ++i) {
        int c = T + i * 256;
        int row = c >> 5, slot = c & 31;
        int gr = row0 + row;
        if (gr >= M) continue;
        int byte = row * 512 + ((slot * 16) ^ ((row & 15) << 4));
        short8 v = *(const short8*)((const char*)sZ + byte);
        if (res) {
            #pragma unroll
            for (int e = 0; e < 8; ++e) {
                float f = bf2f((unsigned short)v[e]) + bf2f((unsigned short)resv[i][e]);
                v[e] = (short)f2bf(f);
            }
        }
        *(short8*)(out + (size_t)gr * 256 + slot * 8) = v;
    }
}

// ---------------- generic bf16 MFMA GEMM (small shapes: protein, MLP) ----------------

__global__ __launch_bounds__(256) void mfma_gemm(
    const unsigned short* __restrict__ A, const unsigned short* __restrict__ Bt,
    const float* __restrict__ bias, const float* __restrict__ bng,
    const float* __restrict__ bnb, const unsigned short* __restrict__ res,
    unsigned short* __restrict__ out, int M, int K, int NC, int flags)
{
    __shared__ unsigned short sA[2][128 * 32];
    __shared__ unsigned short sB[2][128 * 32];
    const int T = threadIdx.x;
    const int lane = T & 63;
    const int w = T >> 6, wr = w >> 1, wc = w & 1;
    const int row0 = blockIdx.x * 128;
    const int col0 = blockIdx.y * 128;
    const int nt = K >> 5;

    floatx4 acc[4][4];
    #pragma unroll
    for (int m = 0; m < 4; ++m)
        #pragma unroll
        for (int n = 0; n < 4; ++n)
            acc[m][n] = (floatx4){0.f, 0.f, 0.f, 0.f};

    auto stage = [&](int buf, int k0) {
        #pragma unroll
        for (int it = 0; it < 2; ++it) {
            int c = T + it * 256;
            int r = c >> 2, p = c & 3;
            int gr = row0 + r; if (gr > M - 1) gr = M - 1;
            const unsigned short* gA = A + (size_t)gr * K + k0 + p * 8;
            __builtin_amdgcn_global_load_lds(
                (const __attribute__((address_space(1))) void*)gA,
                (__attribute__((address_space(3))) void*)&sA[buf][c * 8], 16, 0, 0);
            const unsigned short* gB = Bt + (size_t)(col0 + r) * K + k0 + p * 8;
            __builtin_amdgcn_global_load_lds(
                (const __attribute__((address_space(1))) void*)gB,
                (__attribute__((address_space(3))) void*)&sB[buf][c * 8], 16, 0, 0);
        }
    };

    auto compute = [&](int buf) {
        const int fr = lane & 15;
        const int kh = (lane >> 4) * 8;
        short8 af[4], bv[4];
        #pragma unroll
        for (int m = 0; m < 4; ++m)
            af[m] = *(const short8*)&sA[buf][(wr * 64 + m * 16 + fr) * 32 + kh];
        #pragma unroll
        for (int n = 0; n < 4; ++n)
            bv[n] = *(const short8*)&sB[buf][(wc * 64 + n * 16 + fr) * 32 + kh];
        #pragma unroll
        for (int m = 0; m < 4; ++m)
            #pragma unroll
            for (int n = 0; n < 4; ++n)
                acc[m][n] = __builtin_amdgcn_mfma_f32_16x16x32_bf16(af[m], bv[n], acc[m][n], 0, 0, 0);
    };

    stage(0, 0);
    __syncthreads();
    int cur = 0;
    for (int t = 0; t < nt - 1; ++t) {
        stage(cur ^ 1, (t + 1) * 32);
        compute(cur);
        __syncthreads();
        cur ^= 1;
    }
    compute(cur);

    const int crow = (lane >> 4) * 4;
    const int ccol = lane & 15;
    const float inv = rsqrtf(1.f + 1e-5f);
    #pragma unroll
    for (int n = 0; n < 4; ++n) {
        int col = col0 + wc * 64 + n * 16 + ccol;
        float bb = bias ? bias[col] : 0.f;
        float sc = 1.f, be = 0.f;
        if (flags & FLAG_BN) { sc = bng[col] * inv; be = bnb[col]; }
        #pragma unroll
        for (int m = 0; m < 4; ++m) {
            #pragma unroll
            for (int j = 0; j < 4; ++j) {
                int r = row0 + wr * 64 + m * 16 + crow + j;
                if (r >= M) continue;
                float y = acc[m][n][j] + bb;
                if (flags & FLAG_BN) y = y * sc + be;
                if (flags & FLAG_RELU) y = fmaxf(y, 0.f);
                if (flags & FLAG_RES) y += bf2f(res[(size_t)r * NC + col]);
                out[(size_t)r * NC + col] = f2bf(y);
            }
        }
    }
}

// ---------------- pooling, LN, final dot ----------------

__global__ void pool_kernel(const unsigned short* __restrict__ h, const int* __restrict__ goffs,
                            unsigned short* __restrict__ out, int ldout) {
    int g = blockIdx.x;
    int f = threadIdx.x;
    int s = goffs[g], e = goffs[g + 1];
    float acc = 0.f;
    for (int i = s; i < e; ++i) acc += bf2f(h[(size_t)i * 256 + f]);
    out[(size_t)g * ldout + f] = f2bf(acc);
}

__global__ void ln_relu_kernel(const unsigned short* __restrict__ p, const float* __restrict__ g,
                               const float* __restrict__ b, unsigned short* __restrict__ out, int ldout) {
    int row = blockIdx.x;
    int t = threadIdx.x; // 256
    float v = bf2f(p[(size_t)row * 256 + t]);
    float s1 = v, s2 = v * v;
    #pragma unroll
    for (int o = 32; o > 0; o >>= 1) { s1 += __shfl_xor(s1, o); s2 += __shfl_xor(s2, o); }
    __shared__ float as1[4], as2[4];
    int w = t >> 6, lane = t & 63;
    if (lane == 0) { as1[w] = s1; as2[w] = s2; }
    __syncthreads();
    float tot1 = as1[0] + as1[1] + as1[2] + as1[3];
    float tot2 = as2[0] + as2[1] + as2[2] + as2[3];
    float mean = tot1 * (1.f / 256.f);
    float var = tot2 * (1.f / 256.f) - mean * mean;
    float y = (v - mean) * rsqrtf(var + 1e-5f) * g[t] + b[t];
    out[(size_t)row * ldout + t] = f2bf(fmaxf(y, 0.f));
}

__global__ void pred3_kernel(const unsigned short* __restrict__ h2, const float* __restrict__ w,
                             const float* __restrict__ b, float* __restrict__ out, int B) {
    int row = blockIdx.x * 4 + (threadIdx.x >> 6);
    int lane = threadIdx.x & 63;
    if (row >= B) return;
    float acc = 0.f;
    #pragma unroll
    for (int k = 0; k < 512; k += 64) acc += bf2f(h2[(size_t)row * 512 + k + lane]) * w[k + lane];
    #pragma unroll
    for (int o = 32; o > 0; o >>= 1) acc += __shfl_xor(acc, o);
    if (lane == 0) out[row] = acc + b[0];
}

// ---------------- host ----------------

extern "C" void kernel_launch(void* const* d_in, const int* in_sizes, int n_in,
                              void* d_out, int out_size, void* d_ws, size_t ws_size,
                              hipStream_t stream) {
    const float* x    = (const float*)d_in[0];
    const int*   ei   = (const int*)d_in[1];
    const int*   batch= (const int*)d_in[2];
    const float* pemb = (const float*)d_in[3];
    const float* g0w1 = (const float*)d_in[4];
    const float* g0b1 = (const float*)d_in[5];
    const float* g0w2 = (const float*)d_in[6];
    const float* g0b2 = (const float*)d_in[7];
    const float* g0g  = (const float*)d_in[8];
    const float* g0be = (const float*)d_in[9];
    const float* gw1  = (const float*)d_in[10];
    const float* gb1  = (const float*)d_in[11];
    const float* gw2  = (const float*)d_in[12];
    const float* gb2  = (const float*)d_in[13];
    const float* gg   = (const float*)d_in[14];
    const float* gbe  = (const float*)d_in[15];
    const float* wp   = (const float*)d_in[16];
    const float* bp   = (const float*)d_in[17];
    const float* lng  = (const float*)d_in[18];
    const float* lnb  = (const float*)d_in[19];
    const float* wpr1 = (const float*)d_in[20];
    const float* bpr1 = (const float*)d_in[21];
    const float* wpr2 = (const float*)d_in[22];
    const float* bpr2 = (const float*)d_in[23];
    const float* wpr3 = (const float*)d_in[24];
    const float* bpr3 = (const float*)d_in[25];

    int N = in_sizes[0] / F_ATOM;
    int E = in_sizes[1] / 2;
    int B = in_sizes[3] / 480;

    char* wsp = (char*)d_ws;
    auto carve = [&](size_t bytes) {
        void* p = (void*)wsp;
        wsp += (bytes + 255) & ~(size_t)255;
        return p;
    };
    int* offs    = (int*)carve((size_t)(N + 1) * 4);
    int* cursor  = (int*)carve((size_t)N * 4);
    int* partial = (int*)carve((size_t)1025 * 4);
    int* ssrc    = (int*)carve((size_t)E * 4);
    int* goffs   = (int*)carve((size_t)(B + 1) * 4);
    unsigned short* xb   = (unsigned short*)carve((size_t)N * 80 * 2);
    unsigned short* z0   = (unsigned short*)carve((size_t)N * 128 * 2);
    unsigned short* hbuf = (unsigned short*)carve((size_t)N * 256 * 2);
    unsigned short* tbuf = (unsigned short*)carve((size_t)N * 256 * 2);
    unsigned short* zbuf = (unsigned short*)carve((size_t)N * 256 * 2);
    unsigned short* pembbf = (unsigned short*)carve((size_t)B * 480 * 2);
    unsigned short* ptmp = (unsigned short*)carve((size_t)B * 256 * 2);
    unsigned short* cat  = (unsigned short*)carve((size_t)B * 512 * 2);
    unsigned short* h1   = (unsigned short*)carve((size_t)B * 1024 * 2);
    unsigned short* h2   = (unsigned short*)carve((size_t)B * 512 * 2);
    unsigned short* w10t = (unsigned short*)carve((size_t)256 * 128 * 2);
    unsigned short* w20t = (unsigned short*)carve((size_t)256 * 256 * 2);
    unsigned short* w1t  = (unsigned short*)carve((size_t)3 * 256 * 256 * 2);
    unsigned short* w2t  = (unsigned short*)carve((size_t)3 * 256 * 256 * 2);
    unsigned short* wpt  = (unsigned short*)carve((size_t)256 * 480 * 2);
    unsigned short* wpr1t= (unsigned short*)carve((size_t)1024 * 512 * 2);
    unsigned short* wpr2t= (unsigned short*)carve((size_t)512 * 1024 * 2);

    const int* srcp = ei;
    const int* dstp = ei + E;

    // CSR by dst: count -> 3-kernel scan -> fill (atomicSub on counts, no 2nd memset)
    hipMemsetAsync(cursor, 0, (size_t)N * 4, stream);
    count_kernel<<<(E + 255) / 256, 256, 0, stream>>>(dstp, cursor, E);
    int nb = (N + 1023) / 1024;
    scan_sum_kernel<<<nb, 256, 0, stream>>>(cursor, partial, N);
    scan_part_kernel<<<1, 1024, 0, stream>>>(partial, nb);
    scan_apply_kernel<<<nb, 256, 0, stream>>>(cursor, partial, offs, N, nb);
    fill_kernel<<<(E + 255) / 256, 256, 0, stream>>>(srcp, dstp, offs, cursor, ssrc, E);
    graph_bounds_kernel<<<(B + 256) / 256, 256, 0, stream>>>(batch, goffs, N, B);

    // unified prep (all converts + transposes, one dispatch)
    prep_kernel<<<2048, 256, 0, stream>>>(x, pemb, g0w1, g0w2, gw1, gw2, wp, wpr1, wpr2,
                                          xb, pembbf, w10t, w20t, w1t, w2t, wpt, wpr1t, wpr2t,
                                          N, B);

    int rbN = (N + 63) / 64;

    // layer 0 (70 -> 256)
    agg0b_kernel<<<(N + 15) / 16, 256, 0, stream>>>(xb, offs, ssrc, z0, N);
    fused_gin<128><<<rbN, 256, 0, stream>>>(z0, w10t, g0b1, w20t, g0b2, g0g, g0be,
                                            nullptr, hbuf, N);

    // layers 1..3 with residual
    unsigned short* H = hbuf; unsigned short* T2 = tbuf;
    for (int i = 0; i < 3; ++i) {
        agg_bf16_kernel<<<(N + 7) / 8, 256, 0, stream>>>(H, offs, ssrc, zbuf, N);
        fused_gin<256><<<rbN, 256, 0, stream>>>(zbuf, w1t + (size_t)i * 65536, gb1 + i * 256,
                                                w2t + (size_t)i * 65536, gb2 + i * 256,
                                                gg + i * 256, gbe + i * 256, H, T2, N);
        unsigned short* tmp = H; H = T2; T2 = tmp;
    }

    // pool -> cat[:, 0:256]
    pool_kernel<<<B, 256, 0, stream>>>(H, goffs, cat, 512);

    // protein projector -> cat[:, 256:512]
    mfma_gemm<<<dim3((B + 127) / 128, 2), 256, 0, stream>>>(pembbf, wpt, bp, nullptr, nullptr, nullptr,
                                                            ptmp, B, 480, 256, 0);
    ln_relu_kernel<<<B, 256, 0, stream>>>(ptmp, lng, lnb, cat + 256, 512);

    // predictor MLP
    mfma_gemm<<<dim3((B + 127) / 128, 8), 256, 0, stream>>>(cat, wpr1t, bpr1, nullptr, nullptr, nullptr,
                                                            h1, B, 512, 1024, FLAG_RELU);
    mfma_gemm<<<dim3((B + 127) / 128, 4), 256, 0, stream>>>(h1, wpr2t, bpr2, nullptr, nullptr, nullptr,
                                                            h2, B, 1024, 512, FLAG_RELU);
    pred3_kernel<<<(B + 3) / 4, 256, 0, stream>>>(h2, wpr3, bpr3, (float*)d_out, B);
}

// Round 10
// 519.411 us; speedup vs baseline: 1.1133x; 1.1077x over previous
//
#include <hip/hip_runtime.h>

#define F_ATOM 70

#define FLAG_RELU 1
#define FLAG_BN   2
#define FLAG_RES  4

typedef __attribute__((ext_vector_type(8))) short short8;
typedef __attribute__((ext_vector_type(4))) float floatx4;

__device__ __forceinline__ float bf2f(unsigned short u) {
    union { unsigned int i; float f; } x; x.i = (unsigned int)u << 16; return x.f;
}
__device__ __forceinline__ unsigned short f2bf(float f) {
    union { float f; unsigned int i; } x; x.f = f;
    unsigned int r = x.i + 0x7fffu + ((x.i >> 16) & 1u);
    return (unsigned short)(r >> 16);
}
__device__ __forceinline__ float blo(unsigned int u){ union{unsigned int a; float f;}x; x.a=u<<16; return x.f; }
__device__ __forceinline__ float bhi(unsigned int u){ union{unsigned int a; float f;}x; x.a=u&0xffff0000u; return x.f; }

// ---------------- CSR build ----------------

__global__ void count_kernel(const int* __restrict__ dst, int* __restrict__ cnt, int E) {
    int i = blockIdx.x * blockDim.x + threadIdx.x;
    if (i < E) atomicAdd(&cnt[dst[i]], 1);
}

// 3-kernel parallel exclusive scan over cnt[0..n) -> offs[0..n]
__global__ void scan_sum_kernel(const int* __restrict__ cnt, int* __restrict__ partial, int n) {
    int t = threadIdx.x;
    int base = blockIdx.x * 1024 + t * 4;
    int v = 0;
    #pragma unroll
    for (int i = 0; i < 4; ++i) if (base + i < n) v += cnt[base + i];
    #pragma unroll
    for (int o = 32; o > 0; o >>= 1) v += __shfl_down(v, o);
    __shared__ int ws[4];
    if ((t & 63) == 0) ws[t >> 6] = v;
    __syncthreads();
    if (t == 0) partial[blockIdx.x] = ws[0] + ws[1] + ws[2] + ws[3];
}

__global__ void scan_part_kernel(int* __restrict__ partial, int nb) {
    int t = threadIdx.x, lane = t & 63, w = t >> 6;
    int v = (t < nb) ? partial[t] : 0;
    int s = v;
    #pragma unroll
    for (int o = 1; o < 64; o <<= 1) { int x = __shfl_up(s, o); if (lane >= o) s += x; }
    __shared__ int wsum[16];
    if (lane == 63) wsum[w] = s;
    __syncthreads();
    int woff = 0;
    #pragma unroll
    for (int i = 0; i < 16; ++i) woff += (i < w) ? wsum[i] : 0;
    if (t < nb) partial[t] = woff + s - v;
    if (t == 1023) partial[nb] = woff + s;
}

__global__ void scan_apply_kernel(const int* __restrict__ cnt, const int* __restrict__ partial,
                                  int* __restrict__ offs, int n, int nb) {
    int t = threadIdx.x;
    int base = blockIdx.x * 1024 + t * 4;
    int v[4];
    #pragma unroll
    for (int i = 0; i < 4; ++i) v[i] = (base + i < n) ? cnt[base + i] : 0;
    int tsum = v[0] + v[1] + v[2] + v[3];
    int lane = t & 63, w = t >> 6;
    int s = tsum;
    #pragma unroll
    for (int o = 1; o < 64; o <<= 1) { int x = __shfl_up(s, o); if (lane >= o) s += x; }
    __shared__ int wsum[4];
    if (lane == 63) wsum[w] = s;
    __syncthreads();
    int woff = 0;
    #pragma unroll
    for (int i = 0; i < 4; ++i) woff += (i < w) ? wsum[i] : 0;
    int run = partial[blockIdx.x] + woff + s - tsum;
    #pragma unroll
    for (int i = 0; i < 4; ++i) { if (base + i < n) offs[base + i] = run; run += v[i]; }
    if (blockIdx.x == 0 && t == 0) offs[n] = partial[nb];
}

// fill via atomicSub on counts (cursor holds per-node counts after count_kernel)
__global__ void fill_kernel(const int* __restrict__ src, const int* __restrict__ dst,
                            const int* __restrict__ offs, int* __restrict__ cursor,
                            int* __restrict__ ssrc, int E) {
    int i = blockIdx.x * blockDim.x + threadIdx.x;
    if (i < E) {
        int d = dst[i];
        int pos = atomicSub(&cursor[d], 1);
        ssrc[offs[d] + pos - 1] = src[i];
    }
}

__global__ void graph_bounds_kernel(const int* __restrict__ batch, int* __restrict__ goffs,
                                    int N, int B) {
    int g = blockIdx.x * blockDim.x + threadIdx.x;
    if (g > B) return;
    int lo = 0, hi = N;
    while (lo < hi) {
        int mid = (lo + hi) >> 1;
        if (batch[mid] < g) lo = mid + 1; else hi = mid;
    }
    goffs[g] = lo;
}

// -------- unified prep: all fp32->bf16 conversions + weight transposes, one dispatch ----

__global__ __launch_bounds__(256) void prep_kernel(
    const float* __restrict__ x, const float* __restrict__ pemb,
    const float* __restrict__ g0w1, const float* __restrict__ g0w2,
    const float* __restrict__ gw1, const float* __restrict__ gw2,
    const float* __restrict__ wp, const float* __restrict__ wpr1, const float* __restrict__ wpr2,
    unsigned short* __restrict__ xb, unsigned short* __restrict__ pembbf,
    unsigned short* __restrict__ w10t, unsigned short* __restrict__ w20t,
    unsigned short* __restrict__ w1t, unsigned short* __restrict__ w2t,
    unsigned short* __restrict__ wpt, unsigned short* __restrict__ wpr1t,
    unsigned short* __restrict__ wpr2t, int N, int B)
{
    const long long sz0 = (long long)N * 80;
    const long long sz1 = (long long)B * 480;
    const long long szw10 = 256 * 128, szw20 = 256 * 256;
    const long long szw1 = 3 * 256 * 256, szw2 = 3 * 256 * 256;
    const long long szwp = 256 * 480, szp1 = 1024 * 512, szp2 = 512 * 1024;
    const long long total = sz0 + sz1 + szw10 + szw20 + szw1 + szw2 + szwp + szp1 + szp2;
    const long long stride = (long long)gridDim.x * blockDim.x;
    for (long long idx = (long long)blockIdx.x * blockDim.x + threadIdx.x; idx < total; idx += stride) {
        long long r = idx;
        if (r < sz0) {
            int node = (int)(r / 80), f = (int)(r - (long long)node * 80);
            xb[r] = f2bf(f < F_ATOM ? x[(long long)node * F_ATOM + f] : 0.f);
            continue;
        }
        r -= sz0;
        if (r < sz1) { pembbf[r] = f2bf(pemb[r]); continue; }
        r -= sz1;
        if (r < szw10) {
            int nr = (int)(r >> 7), k = (int)(r & 127);
            w10t[r] = f2bf(k < F_ATOM ? g0w1[k * 256 + nr] : 0.f);
            continue;
        }
        r -= szw10;
        if (r < szw20) {
            int nr = (int)(r >> 8), k = (int)(r & 255);
            w20t[r] = f2bf(g0w2[k * 256 + nr]);
            continue;
        }
        r -= szw20;
        if (r < szw1) {
            int l = (int)(r >> 16); int r2 = (int)(r & 65535);
            int nr = r2 >> 8, k = r2 & 255;
            w1t[r] = f2bf(gw1[(size_t)l * 65536 + k * 256 + nr]);
            continue;
        }
        r -= szw1;
        if (r < szw2) {
            int l = (int)(r >> 16); int r2 = (int)(r & 65535);
            int nr = r2 >> 8, k = r2 & 255;
            w2t[r] = f2bf(gw2[(size_t)l * 65536 + k * 256 + nr]);
            continue;
        }
        r -= szw2;
        if (r < szwp) {
            int nr = (int)(r / 480), k = (int)(r - (long long)nr * 480);
            wpt[r] = f2bf(wp[k * 256 + nr]);
            continue;
        }
        r -= szwp;
        if (r < szp1) {
            int nr = (int)(r >> 9), k = (int)(r & 511);
            wpr1t[r] = f2bf(wpr1[k * 1024 + nr]);
            continue;
        }
        r -= szp1;
        {
            int nr = (int)(r >> 10), k = (int)(r & 1023);
            wpr2t[r] = f2bf(wpr2[k * 512 + nr]);
        }
    }
}

// ---------------- aggregation (high-occupancy standalone gathers, 8-deep unroll) -------

__global__ __launch_bounds__(256) void agg0b_kernel(
    const unsigned short* __restrict__ xb, const int* __restrict__ offs,
    const int* __restrict__ ssrc, unsigned short* __restrict__ z0, int n) {
    int t = threadIdx.x;
    int node = blockIdx.x * 16 + (t >> 4);
    if (node >= n) return;
    int c = t & 15;
    if (c >= 10) {
        *(uint4*)(z0 + (size_t)node * 128 + c * 8) = make_uint4(0, 0, 0, 0);
        return;
    }
    float a[8];
    {
        uint4 v = *(const uint4*)(xb + (size_t)node * 80 + c * 8);
        a[0]=blo(v.x); a[1]=bhi(v.x); a[2]=blo(v.y); a[3]=bhi(v.y);
        a[4]=blo(v.z); a[5]=bhi(v.z); a[6]=blo(v.w); a[7]=bhi(v.w);
    }
    int s = offs[node], e2 = offs[node + 1];
    int k = s;
    for (; k + 7 < e2; k += 8) {
        uint4 u[8];
        #pragma unroll
        for (int q = 0; q < 8; ++q)
            u[q] = *(const uint4*)(xb + (size_t)ssrc[k + q] * 80 + c * 8);
        #pragma unroll
        for (int q = 0; q < 8; ++q) {
            a[0]+=blo(u[q].x); a[1]+=bhi(u[q].x); a[2]+=blo(u[q].y); a[3]+=bhi(u[q].y);
            a[4]+=blo(u[q].z); a[5]+=bhi(u[q].z); a[6]+=blo(u[q].w); a[7]+=bhi(u[q].w);
        }
    }
    for (; k + 1 < e2; k += 2) {
        uint4 u0 = *(const uint4*)(xb + (size_t)ssrc[k]     * 80 + c * 8);
        uint4 u1 = *(const uint4*)(xb + (size_t)ssrc[k + 1] * 80 + c * 8);
        a[0]+=blo(u0.x); a[1]+=bhi(u0.x); a[2]+=blo(u0.y); a[3]+=bhi(u0.y);
        a[4]+=blo(u0.z); a[5]+=bhi(u0.z); a[6]+=blo(u0.w); a[7]+=bhi(u0.w);
        a[0]+=blo(u1.x); a[1]+=bhi(u1.x); a[2]+=blo(u1.y); a[3]+=bhi(u1.y);
        a[4]+=blo(u1.z); a[5]+=bhi(u1.z); a[6]+=blo(u1.w); a[7]+=bhi(u1.w);
    }
    if (k < e2) {
        uint4 u0 = *(const uint4*)(xb + (size_t)ssrc[k] * 80 + c * 8);
        a[0]+=blo(u0.x); a[1]+=bhi(u0.x); a[2]+=blo(u0.y); a[3]+=bhi(u0.y);
        a[4]+=blo(u0.z); a[5]+=bhi(u0.z); a[6]+=blo(u0.w); a[7]+=bhi(u0.w);
    }
    unsigned int o0 = (unsigned int)f2bf(a[0]) | ((unsigned int)f2bf(a[1]) << 16);
    unsigned int o1 = (unsigned int)f2bf(a[2]) | ((unsigned int)f2bf(a[3]) << 16);
    unsigned int o2 = (unsigned int)f2bf(a[4]) | ((unsigned int)f2bf(a[5]) << 16);
    unsigned int o3 = (unsigned int)f2bf(a[6]) | ((unsigned int)f2bf(a[7]) << 16);
    *(uint4*)(z0 + (size_t)node * 128 + c * 8) = make_uint4(o0, o1, o2, o3);
}

__global__ __launch_bounds__(256) void agg_bf16_kernel(
    const unsigned short* __restrict__ h, const int* __restrict__ offs,
    const int* __restrict__ ssrc, unsigned short* __restrict__ out, int n) {
    int t = threadIdx.x;
    int node = blockIdx.x * 8 + (t >> 5);
    if (node >= n) return;
    int f8 = (t & 31) * 8;
    float a[8];
    {
        uint4 v = *(const uint4*)(h + (size_t)node * 256 + f8);
        a[0]=blo(v.x); a[1]=bhi(v.x); a[2]=blo(v.y); a[3]=bhi(v.y);
        a[4]=blo(v.z); a[5]=bhi(v.z); a[6]=blo(v.w); a[7]=bhi(v.w);
    }
    int s = offs[node], e2 = offs[node + 1];
    int k = s;
    for (; k + 7 < e2; k += 8) {
        uint4 u[8];
        #pragma unroll
        for (int q = 0; q < 8; ++q)
            u[q] = *(const uint4*)(h + (size_t)ssrc[k + q] * 256 + f8);
        #pragma unroll
        for (int q = 0; q < 8; ++q) {
            a[0]+=blo(u[q].x); a[1]+=bhi(u[q].x); a[2]+=blo(u[q].y); a[3]+=bhi(u[q].y);
            a[4]+=blo(u[q].z); a[5]+=bhi(u[q].z); a[6]+=blo(u[q].w); a[7]+=bhi(u[q].w);
        }
    }
    for (; k + 1 < e2; k += 2) {
        uint4 u0 = *(const uint4*)(h + (size_t)ssrc[k]     * 256 + f8);
        uint4 u1 = *(const uint4*)(h + (size_t)ssrc[k + 1] * 256 + f8);
        a[0]+=blo(u0.x); a[1]+=bhi(u0.x); a[2]+=blo(u0.y); a[3]+=bhi(u0.y);
        a[4]+=blo(u0.z); a[5]+=bhi(u0.z); a[6]+=blo(u0.w); a[7]+=bhi(u0.w);
        a[0]+=blo(u1.x); a[1]+=bhi(u1.x); a[2]+=blo(u1.y); a[3]+=bhi(u1.y);
        a[4]+=blo(u1.z); a[5]+=bhi(u1.z); a[6]+=blo(u1.w); a[7]+=bhi(u1.w);
    }
    if (k < e2) {
        uint4 u0 = *(const uint4*)(h + (size_t)ssrc[k] * 256 + f8);
        a[0]+=blo(u0.x); a[1]+=bhi(u0.x); a[2]+=blo(u0.y); a[3]+=bhi(u0.y);
        a[4]+=blo(u0.z); a[5]+=bhi(u0.z); a[6]+=blo(u0.w); a[7]+=bhi(u0.w);
    }
    unsigned int o0 = (unsigned int)f2bf(a[0]) | ((unsigned int)f2bf(a[1]) << 16);
    unsigned int o1 = (unsigned int)f2bf(a[2]) | ((unsigned int)f2bf(a[3]) << 16);
    unsigned int o2 = (unsigned int)f2bf(a[4]) | ((unsigned int)f2bf(a[5]) << 16);
    unsigned int o3 = (unsigned int)f2bf(a[6]) | ((unsigned int)f2bf(a[7]) << 16);
    *(uint4*)(out + (size_t)node * 256 + f8) = make_uint4(o0, o1, o2, o3);
}

// ---------------- fused GIN dual-GEMM (R7-verified: 64 rows, res at writeout) ---------
// out = epi(relu(Z@W1^T + b1) @ W2^T + b2) [+res]. Z: bf16 [M][KSH].
// Block: 64 rows x 256 cols, 256 threads (4 waves; wave wc -> cols wc*64..+64).
// sZ XOR-swizzle: byte_in_row ^= (row & 15) << 4 on both write and read.

template<int KSH>
__global__ __launch_bounds__(256, 4) void fused_gin(
    const unsigned short* __restrict__ Z, const unsigned short* __restrict__ W1,
    const float* __restrict__ b1, const unsigned short* __restrict__ W2,
    const float* __restrict__ b2, const float* __restrict__ bng,
    const float* __restrict__ bnb, const unsigned short* __restrict__ res,
    unsigned short* __restrict__ out, int M)
{
    constexpr int CPR = KSH / 8;    // 16B chunks per row
    constexpr int NT1 = KSH / 32;   // K-chunks in GEMM1
    __shared__ unsigned short sZ[64 * 256];
    const int T = threadIdx.x;
    const int lane = T & 63;
    const int wc = T >> 6;
    const int fr = lane & 15, hi = lane >> 4;
    const int crow = hi * 4;
    const int row0 = blockIdx.x * 64;

    // ---- stage Z tile -> sZ [64][KSH], swizzled source / linear dest ----
    #pragma unroll
    for (int i = 0; i < (64 * CPR) / 256; ++i) {
        int c = T + i * 256;
        int row = c / CPR, p = c % CPR;
        int pp = p ^ (row & 15);
        int gr = row0 + row; if (gr > M - 1) gr = M - 1;
        __builtin_amdgcn_global_load_lds(
            (const __attribute__((address_space(1))) void*)(Z + (size_t)gr * KSH + pp * 8),
            (__attribute__((address_space(3))) void*)&sZ[c * 8], 16, 0, 0);
    }
    __syncthreads();

    floatx4 acc[4][4];
    #pragma unroll
    for (int m = 0; m < 4; ++m)
        #pragma unroll
        for (int n = 0; n < 4; ++n)
            acc[m][n] = (floatx4){0.f, 0.f, 0.f, 0.f};

    // ---- GEMM1: A = sZ [64][KSH], B = W1 direct-from-global, reg double-buffered ----
    {
        short8 cur[4], nxt[4];
        #pragma unroll
        for (int n = 0; n < 4; ++n)
            cur[n] = *(const short8*)(W1 + (size_t)(wc * 64 + n * 16 + fr) * KSH + hi * 8);
        #pragma unroll
        for (int kk = 0; kk < NT1; ++kk) {
            if (kk + 1 < NT1) {
                #pragma unroll
                for (int n = 0; n < 4; ++n)
                    nxt[n] = *(const short8*)(W1 + (size_t)(wc * 64 + n * 16 + fr) * KSH + (kk + 1) * 32 + hi * 8);
            }
            short8 af[4];
            #pragma unroll
            for (int m = 0; m < 4; ++m) {
                int r = m * 16 + fr;
                int byte = r * (KSH * 2) + ((kk * 64 + hi * 16) ^ ((r & 15) << 4));
                af[m] = *(const short8*)((const char*)sZ + byte);
            }
            #pragma unroll
            for (int m = 0; m < 4; ++m)
                #pragma unroll
                for (int n = 0; n < 4; ++n)
                    acc[m][n] = __builtin_amdgcn_mfma_f32_16x16x32_bf16(af[m], cur[n], acc[m][n], 0, 0, 0);
            #pragma unroll
            for (int n = 0; n < 4; ++n) cur[n] = nxt[n];
        }
    }
    __syncthreads();

    // ---- epilogue 1: relu(acc + b1) -> bf16 -> sZ [64][256] xor layout ----
    #pragma unroll
    for (int n = 0; n < 4; ++n) {
        int col = wc * 64 + n * 16 + fr;
        float bb = b1[col];
        #pragma unroll
        for (int m = 0; m < 4; ++m) {
            #pragma unroll
            for (int j = 0; j < 4; ++j) {
                int r = m * 16 + crow + j;
                float y = fmaxf(acc[m][n][j] + bb, 0.f);
                int byte = r * 512 + ((col * 2) ^ ((r & 15) << 4));
                *(unsigned short*)((char*)sZ + byte) = f2bf(y);
            }
        }
    }
    __syncthreads();

    // ---- GEMM2: A = relu1 (sZ [64][256]), B = W2 direct-from-global ----
    #pragma unroll
    for (int m = 0; m < 4; ++m)
        #pragma unroll
        for (int n = 0; n < 4; ++n)
            acc[m][n] = (floatx4){0.f, 0.f, 0.f, 0.f};
    {
        short8 cur[4], nxt[4];
        #pragma unroll
        for (int n = 0; n < 4; ++n)
            cur[n] = *(const short8*)(W2 + (size_t)(wc * 64 + n * 16 + fr) * 256 + hi * 8);
        #pragma unroll
        for (int kk = 0; kk < 8; ++kk) {
            if (kk < 7) {
                #pragma unroll
                for (int n = 0; n < 4; ++n)
                    nxt[n] = *(const short8*)(W2 + (size_t)(wc * 64 + n * 16 + fr) * 256 + (kk + 1) * 32 + hi * 8);
            }
            short8 af[4];
            #pragma unroll
            for (int m = 0; m < 4; ++m) {
                int r = m * 16 + fr;
                int byte = r * 512 + ((kk * 64 + hi * 16) ^ ((r & 15) << 4));
                af[m] = *(const short8*)((const char*)sZ + byte);
            }
            #pragma unroll
            for (int m = 0; m < 4; ++m)
                #pragma unroll
                for (int n = 0; n < 4; ++n)
                    acc[m][n] = __builtin_amdgcn_mfma_f32_16x16x32_bf16(af[m], cur[n], acc[m][n], 0, 0, 0);
            #pragma unroll
            for (int n = 0; n < 4; ++n) cur[n] = nxt[n];
        }
    }
    __syncthreads();   // everyone done reading relu1 before overwrite

    // ---- epilogue 2: BN(acc + b2) -> relu -> bf16 -> sZ ----
    {
        const float inv = rsqrtf(1.f + 1e-5f);
        #pragma unroll
        for (int n = 0; n < 4; ++n) {
            int col = wc * 64 + n * 16 + fr;
            float bb = b2[col];
            float sc = bng[col] * inv, be = bnb[col];
            #pragma unroll
            for (int m = 0; m < 4; ++m) {
                #pragma unroll
                for (int j = 0; j < 4; ++j) {
                    int r = m * 16 + crow + j;
                    float y = (acc[m][n][j] + bb) * sc + be;
                    y = fmaxf(y, 0.f);
                    int byte = r * 512 + ((col * 2) ^ ((r & 15) << 4));
                    *(unsigned short*)((char*)sZ + byte) = f2bf(y);
                }
            }
        }
    }
    __syncthreads();

    // ---- write-out: linear, coalesced, fused residual add (R7 structure) ----
    #pragma unroll
    for (int i = 0; i < 8; ++i) {
        int c = T + i * 256;
        int row = c >> 5, slot = c & 31;
        int gr = row0 + row;
        if (gr >= M) continue;
        int byte = row * 512 + ((slot * 16) ^ ((row & 15) << 4));
        short8 v = *(const short8*)((const char*)sZ + byte);
        if (res) {
            short8 rv = *(const short8*)(res + (size_t)gr * 256 + slot * 8);
            #pragma unroll
            for (int e = 0; e < 8; ++e) {
                float f = bf2f((unsigned short)v[e]) + bf2f((unsigned short)rv[e]);
                v[e] = (short)f2bf(f);
            }
        }
        *(short8*)(out + (size_t)gr * 256 + slot * 8) = v;
    }
}

// ---------------- generic bf16 MFMA GEMM (small shapes: protein, MLP) ----------------

__global__ __launch_bounds__(256) void mfma_gemm(
    const unsigned short* __restrict__ A, const unsigned short* __restrict__ Bt,
    const float* __restrict__ bias, const float* __restrict__ bng,
    const float* __restrict__ bnb, const unsigned short* __restrict__ res,
    unsigned short* __restrict__ out, int M, int K, int NC, int flags)
{
    __shared__ unsigned short sA[2][128 * 32];
    __shared__ unsigned short sB[2][128 * 32];
    const int T = threadIdx.x;
    const int lane = T & 63;
    const int w = T >> 6, wr = w >> 1, wc = w & 1;
    const int row0 = blockIdx.x * 128;
    const int col0 = blockIdx.y * 128;
    const int nt = K >> 5;

    floatx4 acc[4][4];
    #pragma unroll
    for (int m = 0; m < 4; ++m)
        #pragma unroll
        for (int n = 0; n < 4; ++n)
            acc[m][n] = (floatx4){0.f, 0.f, 0.f, 0.f};

    auto stage = [&](int buf, int k0) {
        #pragma unroll
        for (int it = 0; it < 2; ++it) {
            int c = T + it * 256;
            int r = c >> 2, p = c & 3;
            int gr = row0 + r; if (gr > M - 1) gr = M - 1;
            const unsigned short* gA = A + (size_t)gr * K + k0 + p * 8;
            __builtin_amdgcn_global_load_lds(
                (const __attribute__((address_space(1))) void*)gA,
                (__attribute__((address_space(3))) void*)&sA[buf][c * 8], 16, 0, 0);
            const unsigned short* gB = Bt + (size_t)(col0 + r) * K + k0 + p * 8;
            __builtin_amdgcn_global_load_lds(
                (const __attribute__((address_space(1))) void*)gB,
                (__attribute__((address_space(3))) void*)&sB[buf][c * 8], 16, 0, 0);
        }
    };

    auto compute = [&](int buf) {
        const int fr = lane & 15;
        const int kh = (lane >> 4) * 8;
        short8 af[4], bv[4];
        #pragma unroll
        for (int m = 0; m < 4; ++m)
            af[m] = *(const short8*)&sA[buf][(wr * 64 + m * 16 + fr) * 32 + kh];
        #pragma unroll
        for (int n = 0; n < 4; ++n)
            bv[n] = *(const short8*)&sB[buf][(wc * 64 + n * 16 + fr) * 32 + kh];
        #pragma unroll
        for (int m = 0; m < 4; ++m)
            #pragma unroll
            for (int n = 0; n < 4; ++n)
                acc[m][n] = __builtin_amdgcn_mfma_f32_16x16x32_bf16(af[m], bv[n], acc[m][n], 0, 0, 0);
    };

    stage(0, 0);
    __syncthreads();
    int cur = 0;
    for (int t = 0; t < nt - 1; ++t) {
        stage(cur ^ 1, (t + 1) * 32);
        compute(cur);
        __syncthreads();
        cur ^= 1;
    }
    compute(cur);

    const int crow = (lane >> 4) * 4;
    const int ccol = lane & 15;
    const float inv = rsqrtf(1.f + 1e-5f);
    #pragma unroll
    for (int n = 0; n < 4; ++n) {
        int col = col0 + wc * 64 + n * 16 + ccol;
        float bb = bias ? bias[col] : 0.f;
        float sc = 1.f, be = 0.f;
        if (flags & FLAG_BN) { sc = bng[col] * inv; be = bnb[col]; }
        #pragma unroll
        for (int m = 0; m < 4; ++m) {
            #pragma unroll
            for (int j = 0; j < 4; ++j) {
                int r = row0 + wr * 64 + m * 16 + crow + j;
                if (r >= M) continue;
                float y = acc[m][n][j] + bb;
                if (flags & FLAG_BN) y = y * sc + be;
                if (flags & FLAG_RELU) y = fmaxf(y, 0.f);
                if (flags & FLAG_RES) y += bf2f(res[(size_t)r * NC + col]);
                out[(size_t)r * NC + col] = f2bf(y);
            }
        }
    }
}

// ---------------- pooling, LN, final dot ----------------

__global__ void pool_kernel(const unsigned short* __restrict__ h, const int* __restrict__ goffs,
                            unsigned short* __restrict__ out, int ldout) {
    int g = blockIdx.x;
    int f = threadIdx.x;
    int s = goffs[g], e = goffs[g + 1];
    float acc = 0.f;
    for (int i = s; i < e; ++i) acc += bf2f(h[(size_t)i * 256 + f]);
    out[(size_t)g * ldout + f] = f2bf(acc);
}

__global__ void ln_relu_kernel(const unsigned short* __restrict__ p, const float* __restrict__ g,
                               const float* __restrict__ b, unsigned short* __restrict__ out, int ldout) {
    int row = blockIdx.x;
    int t = threadIdx.x; // 256
    float v = bf2f(p[(size_t)row * 256 + t]);
    float s1 = v, s2 = v * v;
    #pragma unroll
    for (int o = 32; o > 0; o >>= 1) { s1 += __shfl_xor(s1, o); s2 += __shfl_xor(s2, o); }
    __shared__ float as1[4], as2[4];
    int w = t >> 6, lane = t & 63;
    if (lane == 0) { as1[w] = s1; as2[w] = s2; }
    __syncthreads();
    float tot1 = as1[0] + as1[1] + as1[2] + as1[3];
    float tot2 = as2[0] + as2[1] + as2[2] + as2[3];
    float mean = tot1 * (1.f / 256.f);
    float var = tot2 * (1.f / 256.f) - mean * mean;
    float y = (v - mean) * rsqrtf(var + 1e-5f) * g[t] + b[t];
    out[(size_t)row * ldout + t] = f2bf(fmaxf(y, 0.f));
}

__global__ void pred3_kernel(const unsigned short* __restrict__ h2, const float* __restrict__ w,
                             const float* __restrict__ b, float* __restrict__ out, int B) {
    int row = blockIdx.x * 4 + (threadIdx.x >> 6);
    int lane = threadIdx.x & 63;
    if (row >= B) return;
    float acc = 0.f;
    #pragma unroll
    for (int k = 0; k < 512; k += 64) acc += bf2f(h2[(size_t)row * 512 + k + lane]) * w[k + lane];
    #pragma unroll
    for (int o = 32; o > 0; o >>= 1) acc += __shfl_xor(acc, o);
    if (lane == 0) out[row] = acc + b[0];
}

// ---------------- host ----------------

extern "C" void kernel_launch(void* const* d_in, const int* in_sizes, int n_in,
                              void* d_out, int out_size, void* d_ws, size_t ws_size,
                              hipStream_t stream) {
    const float* x    = (const float*)d_in[0];
    const int*   ei   = (const int*)d_in[1];
    const int*   batch= (const int*)d_in[2];
    const float* pemb = (const float*)d_in[3];
    const float* g0w1 = (const float*)d_in[4];
    const float* g0b1 = (const float*)d_in[5];
    const float* g0w2 = (const float*)d_in[6];
    const float* g0b2 = (const float*)d_in[7];
    const float* g0g  = (const float*)d_in[8];
    const float* g0be = (const float*)d_in[9];
    const float* gw1  = (const float*)d_in[10];
    const float* gb1  = (const float*)d_in[11];
    const float* gw2  = (const float*)d_in[12];
    const float* gb2  = (const float*)d_in[13];
    const float* gg   = (const float*)d_in[14];
    const float* gbe  = (const float*)d_in[15];
    const float* wp   = (const float*)d_in[16];
    const float* bp   = (const float*)d_in[17];
    const float* lng  = (const float*)d_in[18];
    const float* lnb  = (const float*)d_in[19];
    const float* wpr1 = (const float*)d_in[20];
    const float* bpr1 = (const float*)d_in[21];
    const float* wpr2 = (const float*)d_in[22];
    const float* bpr2 = (const float*)d_in[23];
    const float* wpr3 = (const float*)d_in[24];
    const float* bpr3 = (const float*)d_in[25];

    int N = in_sizes[0] / F_ATOM;
    int E = in_sizes[1] / 2;
    int B = in_sizes[3] / 480;

    char* wsp = (char*)d_ws;
    auto carve = [&](size_t bytes) {
        void* p = (void*)wsp;
        wsp += (bytes + 255) & ~(size_t)255;
        return p;
    };
    int* offs    = (int*)carve((size_t)(N + 1) * 4);
    int* cursor  = (int*)carve((size_t)N * 4);
    int* partial = (int*)carve((size_t)1025 * 4);
    int* ssrc    = (int*)carve((size_t)E * 4);
    int* goffs   = (int*)carve((size_t)(B + 1) * 4);
    unsigned short* xb   = (unsigned short*)carve((size_t)N * 80 * 2);
    unsigned short* z0   = (unsigned short*)carve((size_t)N * 128 * 2);
    unsigned short* hbuf = (unsigned short*)carve((size_t)N * 256 * 2);
    unsigned short* tbuf = (unsigned short*)carve((size_t)N * 256 * 2);
    unsigned short* zbuf = (unsigned short*)carve((size_t)N * 256 * 2);
    unsigned short* pembbf = (unsigned short*)carve((size_t)B * 480 * 2);
    unsigned short* ptmp = (unsigned short*)carve((size_t)B * 256 * 2);
    unsigned short* cat  = (unsigned short*)carve((size_t)B * 512 * 2);
    unsigned short* h1   = (unsigned short*)carve((size_t)B * 1024 * 2);
    unsigned short* h2   = (unsigned short*)carve((size_t)B * 512 * 2);
    unsigned short* w10t = (unsigned short*)carve((size_t)256 * 128 * 2);
    unsigned short* w20t = (unsigned short*)carve((size_t)256 * 256 * 2);
    unsigned short* w1t  = (unsigned short*)carve((size_t)3 * 256 * 256 * 2);
    unsigned short* w2t  = (unsigned short*)carve((size_t)3 * 256 * 256 * 2);
    unsigned short* wpt  = (unsigned short*)carve((size_t)256 * 480 * 2);
    unsigned short* wpr1t= (unsigned short*)carve((size_t)1024 * 512 * 2);
    unsigned short* wpr2t= (unsigned short*)carve((size_t)512 * 1024 * 2);

    const int* srcp = ei;
    const int* dstp = ei + E;

    // CSR by dst: count -> 3-kernel scan -> fill (atomicSub on counts, no 2nd memset)
    hipMemsetAsync(cursor, 0, (size_t)N * 4, stream);
    count_kernel<<<(E + 255) / 256, 256, 0, stream>>>(dstp, cursor, E);
    int nb = (N + 1023) / 1024;
    scan_sum_kernel<<<nb, 256, 0, stream>>>(cursor, partial, N);
    scan_part_kernel<<<1, 1024, 0, stream>>>(partial, nb);
    scan_apply_kernel<<<nb, 256, 0, stream>>>(cursor, partial, offs, N, nb);
    fill_kernel<<<(E + 255) / 256, 256, 0, stream>>>(srcp, dstp, offs, cursor, ssrc, E);
    graph_bounds_kernel<<<(B + 256) / 256, 256, 0, stream>>>(batch, goffs, N, B);

    // unified prep (all converts + transposes, one dispatch)
    prep_kernel<<<2048, 256, 0, stream>>>(x, pemb, g0w1, g0w2, gw1, gw2, wp, wpr1, wpr2,
                                          xb, pembbf, w10t, w20t, w1t, w2t, wpt, wpr1t, wpr2t,
                                          N, B);

    int rbN = (N + 63) / 64;

    // layer 0 (70 -> 256)
    agg0b_kernel<<<(N + 15) / 16, 256, 0, stream>>>(xb, offs, ssrc, z0, N);
    fused_gin<128><<<rbN, 256, 0, stream>>>(z0, w10t, g0b1, w20t, g0b2, g0g, g0be,
                                            nullptr, hbuf, N);

    // layers 1..3 with residual
    unsigned short* H = hbuf; unsigned short* T2 = tbuf;
    for (int i = 0; i < 3; ++i) {
        agg_bf16_kernel<<<(N + 7) / 8, 256, 0, stream>>>(H, offs, ssrc, zbuf, N);
        fused_gin<256><<<rbN, 256, 0, stream>>>(zbuf, w1t + (size_t)i * 65536, gb1 + i * 256,
                                                w2t + (size_t)i * 65536, gb2 + i * 256,
                                                gg + i * 256, gbe + i * 256, H, T2, N);
        unsigned short* tmp = H; H = T2; T2 = tmp;
    }

    // pool -> cat[:, 0:256]
    pool_kernel<<<B, 256, 0, stream>>>(H, goffs, cat, 512);

    // protein projector -> cat[:, 256:512]
    mfma_gemm<<<dim3((B + 127) / 128, 2), 256, 0, stream>>>(pembbf, wpt, bp, nullptr, nullptr, nullptr,
                                                            ptmp, B, 480, 256, 0);
    ln_relu_kernel<<<B, 256, 0, stream>>>(ptmp, lng, lnb, cat + 256, 512);

    // predictor MLP
    mfma_gemm<<<dim3((B + 127) / 128, 8), 256, 0, stream>>>(cat, wpr1t, bpr1, nullptr, nullptr, nullptr,
                                                            h1, B, 512, 1024, FLAG_RELU);
    mfma_gemm<<<dim3((B + 127) / 128, 4), 256, 0, stream>>>(h1, wpr2t, bpr2, nullptr, nullptr, nullptr,
                                                            h2, B, 1024, 512, FLAG_RELU);
    pred3_kernel<<<(B + 3) / 4, 256, 0, stream>>>(h2, wpr3, bpr3, (float*)d_out, B);
}